// Round 6
// baseline (450.114 us; speedup 1.0000x reference)
//
#include <hip/hip_runtime.h>
#include <math.h>

#define T_BATCH 128
#define N_TOK   256
#define C_DIM   1408
#define CN1     16
#define KNN1    8
#define CN2     6
#define KNN2    3
#define NOUT    22   // CN2 + CN1
#define LS      40   // LDS row stride in shorts: 80B -> every row 16B-aligned
#define NKS     44   // C_DIM / 32

typedef __attribute__((ext_vector_type(4))) short sh4;
typedef __attribute__((ext_vector_type(8))) short sh8;
typedef __attribute__((ext_vector_type(4))) float f32x4;
typedef __fp16 h2v __attribute__((ext_vector_type(2)));
typedef __fp16 h8v __attribute__((ext_vector_type(8)));

union h2u { h2v h; unsigned u; };

// f16 two-term split of a float4: hi = rtz-f16 of f, lo = rtz-f16 of (f - hi).
// Error per product ~2^-22 relative; hh+hl+lh MFMA terms recover ~22 bits.
__device__ inline void cvt4_f16(const float4 f, uint2& vh, uint2& vl) {
    h2v h0 = __builtin_amdgcn_cvt_pkrtz(f.x, f.y);
    h2v h1 = __builtin_amdgcn_cvt_pkrtz(f.z, f.w);
    float l0 = f.x - (float)h0[0];
    float l1 = f.y - (float)h0[1];
    float l2 = f.z - (float)h1[0];
    float l3 = f.w - (float)h1[1];
    h2v g0 = __builtin_amdgcn_cvt_pkrtz(l0, l1);
    h2v g1 = __builtin_amdgcn_cvt_pkrtz(l2, l3);
    h2u a0, a1, b0, b1;
    a0.h = h0; a1.h = h1; b0.h = g0; b1.h = g1;
    vh.x = a0.u; vh.y = a1.u;
    vl.x = b0.u; vl.y = b1.u;
}

// branchless insert of v into ascending 8-list m (keeps 8 smallest)
#define INS8(m, v) {                                   \
    float _x = (v);                                    \
    _Pragma("unroll")                                  \
    for (int _q = 0; _q < 8; _q++) {                   \
        float _lo = fminf(m[_q], _x);                  \
        _x = fmaxf(m[_q], _x);                         \
        m[_q] = _lo;                                   \
    }                                                  \
}

// ---------------------------------------------------------------------------
// Kernel A: dist via f16x2-split MFMA, 64x64 tiles, upper-tri pairs only.
// v2-proven structure: grid 1280 (XCD-swizzled, 10 blocks/batch), 256 thr,
// 4 blocks/CU so other blocks' waves hide each block's barriers.
// This round's local fixes: coalesced staging (wave = 8 rows x 128B),
// f16-split convert (cheap), LS=40 so each fragment is ONE aligned
// ds_read_b128 (bank-optimal). T14: k+1 loads issue before ds_read/MFMA.
// ---------------------------------------------------------------------------
__global__ __launch_bounds__(256, 4) void gemm_dist_tri(const float* __restrict__ x,
                                                        float* __restrict__ dist) {
    const int id = blockIdx.x;
    const int r  = id & 7;
    const int q8 = id >> 3;          // 0..159
    const int p  = q8 % 10;
    const int tt = q8 / 10;          // 0..15
    const int t  = tt * 8 + r;
    const int bi = (p < 4) ? 0 : (p < 7) ? 1 : (p < 9) ? 2 : 3;
    const int bj = (p < 4) ? p : (p < 7) ? p - 3 : (p < 9) ? p - 5 : 3;
    const int i0 = bi * 64, j0 = bj * 64;
    const bool diag = (bi == bj);
    const float* X = x + (size_t)t * N_TOK * C_DIM;

    __shared__ short Ahi[64 * LS], Alo[64 * LS], Bhi[64 * LS], Blo[64 * LS];
    __shared__ float nrA[64][8], nrB[64][8];
    __shared__ float snA[64], snB[64];

    const int tid  = threadIdx.x;
    const int wave = tid >> 6;       // 0..3
    const int lane = tid & 63;
    const int qr   = wave >> 1;
    const int qc   = wave & 1;
    const int rA   = tid >> 3;       // 0..31 (staging row; also +32)
    const int c8   = tid & 7;        // float4 slot within 32-float K-chunk
    const int fr   = lane & 15;
    const int fq   = lane >> 4;

    const short* BhiS = diag ? Ahi : Bhi;
    const short* BloS = diag ? Alo : Blo;

    f32x4 acc[2][2];
#pragma unroll
    for (int a = 0; a < 2; a++)
#pragma unroll
        for (int b = 0; b < 2; b++) acc[a][b] = (f32x4){0.f, 0.f, 0.f, 0.f};

    const float* A0 = X + (size_t)(i0 + rA) * C_DIM + c8 * 4;
    const float* A1 = X + (size_t)(i0 + rA + 32) * C_DIM + c8 * 4;
    const float* B0 = X + (size_t)(j0 + rA) * C_DIM + c8 * 4;
    const float* B1 = X + (size_t)(j0 + rA + 32) * C_DIM + c8 * 4;
    float nA0 = 0.f, nA1 = 0.f, nB0 = 0.f, nB1 = 0.f;

    // ---- prologue: preload K-chunk 0 ----
    float4 fa0 = *(const float4*)(A0);
    float4 fa1 = *(const float4*)(A1);
    float4 fb0 = {0.f, 0.f, 0.f, 0.f}, fb1 = {0.f, 0.f, 0.f, 0.f};
    if (!diag) {
        fb0 = *(const float4*)(B0);
        fb1 = *(const float4*)(B1);
    }

    for (int ks = 0; ks < NKS; ks++) {
        // convert current regs
        uint2 ah0, al0, ah1, al1, bh0, bl0, bh1, bl1;
        nA0 += fa0.x * fa0.x + fa0.y * fa0.y + fa0.z * fa0.z + fa0.w * fa0.w;
        nA1 += fa1.x * fa1.x + fa1.y * fa1.y + fa1.z * fa1.z + fa1.w * fa1.w;
        cvt4_f16(fa0, ah0, al0);
        cvt4_f16(fa1, ah1, al1);
        if (!diag) {
            nB0 += fb0.x * fb0.x + fb0.y * fb0.y + fb0.z * fb0.z + fb0.w * fb0.w;
            nB1 += fb1.x * fb1.x + fb1.y * fb1.y + fb1.z * fb1.z + fb1.w * fb1.w;
            cvt4_f16(fb0, bh0, bl0);
            cvt4_f16(fb1, bh1, bl1);
        }
        __syncthreads();   // previous K-step's reads complete
        *(uint2*)&Ahi[rA * LS + c8 * 4]        = ah0;
        *(uint2*)&Alo[rA * LS + c8 * 4]        = al0;
        *(uint2*)&Ahi[(rA + 32) * LS + c8 * 4] = ah1;
        *(uint2*)&Alo[(rA + 32) * LS + c8 * 4] = al1;
        if (!diag) {
            *(uint2*)&Bhi[rA * LS + c8 * 4]        = bh0;
            *(uint2*)&Blo[rA * LS + c8 * 4]        = bl0;
            *(uint2*)&Bhi[(rA + 32) * LS + c8 * 4] = bh1;
            *(uint2*)&Blo[(rA + 32) * LS + c8 * 4] = bl1;
        }
        __syncthreads();   // panel visible

        // T14: issue next K-chunk's loads before ds_read/MFMA
        const int k1 = (ks + 1) * 32;
        if (k1 < C_DIM) {
            fa0 = *(const float4*)(A0 + k1);
            fa1 = *(const float4*)(A1 + k1);
            if (!diag) {
                fb0 = *(const float4*)(B0 + k1);
                fb1 = *(const float4*)(B1 + k1);
            }
        }

        h8v fAh[2], fAl[2], fBh[2], fBl[2];
#pragma unroll
        for (int mt = 0; mt < 2; mt++) {
            int ro = (qr * 32 + mt * 16 + fr) * LS + fq * 8;
            fAh[mt] = *(const h8v*)&Ahi[ro];
            fAl[mt] = *(const h8v*)&Alo[ro];
            int co = (qc * 32 + mt * 16 + fr) * LS + fq * 8;
            fBh[mt] = *(const h8v*)&BhiS[co];
            fBl[mt] = *(const h8v*)&BloS[co];
        }
#pragma unroll
        for (int mt = 0; mt < 2; mt++)
#pragma unroll
            for (int nt = 0; nt < 2; nt++) {
                acc[mt][nt] = __builtin_amdgcn_mfma_f32_16x16x32_f16(fAh[mt], fBh[nt], acc[mt][nt], 0, 0, 0);
                acc[mt][nt] = __builtin_amdgcn_mfma_f32_16x16x32_f16(fAh[mt], fBl[nt], acc[mt][nt], 0, 0, 0);
                acc[mt][nt] = __builtin_amdgcn_mfma_f32_16x16x32_f16(fAl[mt], fBh[nt], acc[mt][nt], 0, 0, 0);
            }
    }

    // ---- row norms ----
    nrA[rA][c8] = nA0;
    nrA[rA + 32][c8] = nA1;
    nrB[rA][c8] = diag ? nA0 : nB0;
    nrB[rA + 32][c8] = diag ? nA1 : nB1;
    __syncthreads();
    if (tid < 64) {
        float sa = 0.f, sb = 0.f;
#pragma unroll
        for (int c = 0; c < 8; c++) { sa += nrA[tid][c]; sb += nrB[tid][c]; }
        snA[tid] = sa;
        snB[tid] = sb;
    }
    __syncthreads();

    const float inv_sqrtC = 1.0f / sqrtf((float)C_DIM);
    float* Dt = dist + (size_t)t * N_TOK * N_TOK;
#pragma unroll
    for (int mt = 0; mt < 2; mt++)
#pragma unroll
        for (int nt = 0; nt < 2; nt++) {
            int jl = qc * 32 + nt * 16 + fr;
            int jg = j0 + jl;
            float sqj = snB[jl];
            int il0 = qr * 32 + mt * 16 + fq * 4;
            float vv[4];
#pragma unroll
            for (int rr = 0; rr < 4; rr++) {
                int ig = i0 + il0 + rr;
                float d2 = snA[il0 + rr] + sqj - 2.0f * acc[mt][nt][rr];
                float v = (ig == jg) ? 0.0f : sqrtf(fmaxf(d2, 0.0f)) * inv_sqrtC;
                Dt[(size_t)ig * N_TOK + jg] = v;
                vv[rr] = v;
            }
            if (!diag) {
                float4 o; o.x = vv[0]; o.y = vv[1]; o.z = vv[2]; o.w = vv[3];
                *(float4*)&Dt[(size_t)jg * N_TOK + i0 + il0] = o;
            }
        }
}

// ---------------------------------------------------------------------------
// Kernel B: fused layer-1 DPC. 1024 threads/block, one block per batch.
// 4 threads per column (64-row quarter scans), 2 chains each, LDS merge.
// ---------------------------------------------------------------------------
__global__ __launch_bounds__(1024) void dpc1_fused(const float* __restrict__ dist,
                                                   int* __restrict__ memb,
                                                   int* __restrict__ cntg,
                                                   int* __restrict__ offg) {
    const int t    = blockIdx.x;
    const int tid  = threadIdx.x;    // 0..1023
    const int col  = tid & 255;
    const int h    = tid >> 8;       // row quarter 0..3
    const int lane = tid & 63;
    const int wid  = tid >> 6;       // 0..15
    const float* D = dist + (size_t)t * N_TOK * N_TOK;

    __shared__ float dens_s[N_TOK];
    __shared__ float lists[KNN1][1024];
    __shared__ float red[1024];
    __shared__ float rmax16[16];
    __shared__ unsigned long long wred[16];
    __shared__ int centers[CN1];
    __shared__ int bks[N_TOK];
    __shared__ int cnt_s[CN1], off_s[CN1];

    // ---- pass 1: 8 smallest of this quarter-column, 2 chains ----
    float c0[8], c1[8];
#pragma unroll
    for (int q = 0; q < 8; q++) { c0[q] = 3.4e38f; c1[q] = 3.4e38f; }
    float mx = 0.f;
    const float* base = D + (size_t)(h * 64) * N_TOK + col;
    for (int jj = 0; jj < 64; jj += 2) {
        float d0 = base[(size_t)(jj + 0) * N_TOK];
        float d1 = base[(size_t)(jj + 1) * N_TOK];
        mx = fmaxf(mx, fmaxf(d0, d1));
        INS8(c0, d0); INS8(c1, d1);
    }
#pragma unroll
    for (int q = 0; q < 8; q++) { INS8(c0, c1[q]); }
#pragma unroll
    for (int q = 0; q < 8; q++) lists[q][tid] = c0[q];
    // dmax: wave shuffle-reduce, then 16-entry LDS
#pragma unroll
    for (int off = 32; off > 0; off >>= 1) mx = fmaxf(mx, __shfl_xor(mx, off));
    if (lane == 0) rmax16[wid] = mx;
    __syncthreads();
    float dmax = rmax16[0];
#pragma unroll
    for (int w = 1; w < 16; w++) dmax = fmaxf(dmax, rmax16[w]);

    if (h == 0) {
#pragma unroll
        for (int s = 1; s < 4; s++)
#pragma unroll
            for (int q = 0; q < 8; q++) { float v = lists[q][col + s * 256]; INS8(c0, v); }
        float s2 = 0.f;
#pragma unroll
        for (int q = 0; q < 8; q++) s2 += c0[q] * c0[q];
        dens_s[col] = expf(-s2 / (float)KNN1);
    }
    __syncthreads();
    const float dens = dens_s[col];

    // ---- pass 2: parent distance over this quarter, 2 chains ----
    float p0 = dmax, p1 = dmax;
    const float* dsh = dens_s + h * 64;
    for (int jj = 0; jj < 64; jj += 2) {
        float d0 = base[(size_t)(jj + 0) * N_TOK];
        float d1 = base[(size_t)(jj + 1) * N_TOK];
        p0 = (dsh[jj + 0] > dens) ? fminf(p0, d0) : p0;
        p1 = (dsh[jj + 1] > dens) ? fminf(p1, d1) : p1;
    }
    red[tid] = fminf(p0, p1);
    __syncthreads();
    float score = 0.f;
    if (h == 0)
        score = fminf(fminf(red[col], red[col + 256]),
                      fminf(red[col + 512], red[col + 768])) * dens;

    // ---- top-16 (desc, ties -> lowest index) ----
    unsigned long long key = 0;
    if (h == 0)
        key = ((unsigned long long)__float_as_uint(score) << 32) | (unsigned)(65535 - col);
    for (int k = 0; k < CN1; k++) {
        unsigned long long mm = key;
#pragma unroll
        for (int off = 32; off > 0; off >>= 1) {
            unsigned long long o = __shfl_xor(mm, off);
            mm = (o > mm) ? o : mm;
        }
        if (lane == 0) wred[wid] = mm;
        __syncthreads();
        unsigned long long b = wred[0];
#pragma unroll
        for (int w = 1; w < 16; w++) b = (wred[w] > b) ? wred[w] : b;
        int idx = 65535 - (int)(b & 0xFFFFull);
        if (tid == 0) centers[k] = idx;
        if (tid == idx) key = 0;
        __syncthreads();
    }

    // ---- assign + member lists (h==0 threads; barriers unconditional) ----
    int bk = 0;
    if (h == 0) {
        float bd = 3.4e38f;
#pragma unroll
        for (int k = 0; k < CN1; k++) {
            float d = D[(size_t)centers[k] * N_TOK + col];
            if (d < bd) { bd = d; bk = k; }
        }
#pragma unroll
        for (int k = 0; k < CN1; k++) if (col == centers[k]) bk = k;
        bks[col] = bk;
    }
    __syncthreads();
    if (tid < CN1) {
        int c = 0;
        for (int j = 0; j < N_TOK; j++) c += (bks[j] == tid);
        cnt_s[tid] = c;
    }
    __syncthreads();
    if (tid == 0) {
        int o = 0;
        for (int q = 0; q < CN1; q++) { off_s[q] = o; o += cnt_s[q]; }
    }
    __syncthreads();
    if (h == 0) {
        int rank = 0;
        for (int j = 0; j < col; j++) rank += (bks[j] == bk);
        memb[t * N_TOK + off_s[bk] + rank] = col;
    }
    if (tid < CN1) {
        cntg[t * CN1 + tid] = cnt_s[tid];
        offg[t * CN1 + tid] = off_s[tid];
    }
}

// ---------------------------------------------------------------------------
// Kernel C: merge1 via member lists, member loop unrolled x4 (4 independent
// row streams in flight; summation order preserved).
// ---------------------------------------------------------------------------
__global__ __launch_bounds__(256) void merge1_kernel(const float* __restrict__ x,
                                                     const int* __restrict__ memb,
                                                     const int* __restrict__ cntg,
                                                     const int* __restrict__ offg,
                                                     float* __restrict__ meta1) {
    const int q   = blockIdx.x;
    const int t   = blockIdx.y;
    const int tid = threadIdx.x;
    const int n    = cntg[t * CN1 + q];
    const int base = t * N_TOK + offg[t * CN1 + q];
    const int c0 = tid, c1 = tid + 256;
    const bool act1 = (c1 < C_DIM / 4);
    const float4* xb = (const float4*)(x + (size_t)t * N_TOK * C_DIM);
    const int stride4 = C_DIM / 4;

    float4 s0 = {0.f, 0.f, 0.f, 0.f};
    float4 s1 = {0.f, 0.f, 0.f, 0.f};
    int m = 0;
    for (; m + 4 <= n; m += 4) {
        int r0 = memb[base + m + 0];
        int r1 = memb[base + m + 1];
        int r2 = memb[base + m + 2];
        int r3 = memb[base + m + 3];
        float4 a0 = xb[(size_t)r0 * stride4 + c0];
        float4 a1 = xb[(size_t)r1 * stride4 + c0];
        float4 a2 = xb[(size_t)r2 * stride4 + c0];
        float4 a3 = xb[(size_t)r3 * stride4 + c0];
        s0.x += a0.x; s0.y += a0.y; s0.z += a0.z; s0.w += a0.w;
        s0.x += a1.x; s0.y += a1.y; s0.z += a1.z; s0.w += a1.w;
        s0.x += a2.x; s0.y += a2.y; s0.z += a2.z; s0.w += a2.w;
        s0.x += a3.x; s0.y += a3.y; s0.z += a3.z; s0.w += a3.w;
        if (act1) {
            float4 b0 = xb[(size_t)r0 * stride4 + c1];
            float4 b1 = xb[(size_t)r1 * stride4 + c1];
            float4 b2 = xb[(size_t)r2 * stride4 + c1];
            float4 b3 = xb[(size_t)r3 * stride4 + c1];
            s1.x += b0.x; s1.y += b0.y; s1.z += b0.z; s1.w += b0.w;
            s1.x += b1.x; s1.y += b1.y; s1.z += b1.z; s1.w += b1.w;
            s1.x += b2.x; s1.y += b2.y; s1.z += b2.z; s1.w += b2.w;
            s1.x += b3.x; s1.y += b3.y; s1.z += b3.z; s1.w += b3.w;
        }
    }
    for (; m < n; m++) {
        int r0 = memb[base + m];
        float4 a0 = xb[(size_t)r0 * stride4 + c0];
        s0.x += a0.x; s0.y += a0.y; s0.z += a0.z; s0.w += a0.w;
        if (act1) {
            float4 b0 = xb[(size_t)r0 * stride4 + c1];
            s1.x += b0.x; s1.y += b0.y; s1.z += b0.z; s1.w += b0.w;
        }
    }
    float w = 1.0f / ((float)n + 1e-6f);
    float4* mr = (float4*)(meta1 + ((size_t)t * CN1 + q) * C_DIM);
    float4 o0; o0.x = s0.x * w; o0.y = s0.y * w; o0.z = s0.z * w; o0.w = s0.w * w;
    mr[c0] = o0;
    if (act1) {
        float4 o1; o1.x = s1.x * w; o1.y = s1.y * w; o1.z = s1.z * w; o1.w = s1.w * w;
        mr[c1] = o1;
    }
}

// ---------------------------------------------------------------------------
// Kernel DE: layer-2 DPC + merge2 + modulation + grouped output.
// 1024 threads per block, one block per batch.
// ---------------------------------------------------------------------------
__global__ __launch_bounds__(1024) void layer2_kernel(const float* __restrict__ meta1,
                                                      const float* __restrict__ score_w,
                                                      const float* __restrict__ score_b,
                                                      float* __restrict__ out) {
    const int t   = blockIdx.x;
    const int tid = threadIdx.x;   // 0..1023
    const float* M = meta1 + (size_t)t * CN1 * C_DIM;

    __shared__ float buf[CN1][132];
    __shared__ float d2s[CN1][CN1];
    __shared__ float m2[CN2][C_DIM];
    __shared__ float dens[CN1], scor[CN1], nrm[CN1], rmx[CN1];
    __shared__ int   centers[CN2], idx2s[CN1], cnt2[CN2];
    __shared__ float modu[CN2], msum[CN2];
    __shared__ int   srcRow[NOUT], cidArr[NOUT];
    __shared__ float dmax_sh;

    const int ti = (tid < 256) ? (tid >> 4) : 0;
    const int tj = tid & 15;

    // ---- pairwise dots (threads 0-255 own one (i,j) pair; all stage) ----
    float acc = 0.f;
    for (int c0 = 0; c0 < C_DIM; c0 += 128) {
        for (int e = tid; e < CN1 * 128; e += 1024) {
            int r = e >> 7, c = e & 127;
            buf[r][c] = M[(size_t)r * C_DIM + c0 + c];
        }
        __syncthreads();
        if (tid < 256) {
#pragma unroll
            for (int cc = 0; cc < 128; cc += 4) {
                float4 a = *(const float4*)&buf[ti][cc];
                float4 b = *(const float4*)&buf[tj][cc];
                acc += a.x * b.x + a.y * b.y + a.z * b.z + a.w * b.w;
            }
        }
        __syncthreads();
    }
    if (tid < 256 && ti == tj) nrm[ti] = acc;
    __syncthreads();

    const float inv_sqrtC = 1.0f / sqrtf((float)C_DIM);
    if (tid < 256) {
        float d2 = nrm[ti] + nrm[tj] - 2.f * acc;
        d2s[ti][tj] = sqrtf(fmaxf(d2, 0.f)) * inv_sqrtC;
    }
    __syncthreads();

    if (tid < CN1) {
        float m0 = 3.4e38f, m1 = 3.4e38f, m2v = 3.4e38f, mx = 0.f;
        for (int j = 0; j < CN1; j++) {
            float d = d2s[tid][j];
            mx = fmaxf(mx, d);
            if (d < m2v) {
                m2v = d;
                if (m2v < m1) { float tmp = m2v; m2v = m1; m1 = tmp; }
                if (m1 < m0)  { float tmp = m1;  m1 = m0;  m0 = tmp; }
            }
        }
        dens[tid] = expf(-(m0 * m0 + m1 * m1 + m2v * m2v) / (float)KNN2);
        rmx[tid] = mx;
    }
    __syncthreads();
    if (tid == 0) {
        float g = 0.f;
        for (int j = 0; j < CN1; j++) g = fmaxf(g, rmx[j]);
        dmax_sh = g;
    }
    __syncthreads();

    if (tid < CN1) {
        float di = dens[tid];
        float pd = dmax_sh;
        for (int j = 0; j < CN1; j++)
            if (dens[j] > di) pd = fminf(pd, d2s[tid][j]);
        scor[tid] = pd * di;
    }
    __syncthreads();

    if (tid == 0) {
        for (int k = 0; k < CN2; k++) {
            float best = -3.4e38f; int bi = 0;
            for (int j = 0; j < CN1; j++)
                if (scor[j] > best) { best = scor[j]; bi = j; }
            centers[k] = bi;
            scor[bi] = -3.4e38f;
        }
    }
    __syncthreads();

    if (tid < CN1) {
        float bd = 3.4e38f; int bk = 0;
#pragma unroll
        for (int k = 0; k < CN2; k++) {
            float d = d2s[centers[k]][tid];
            if (d < bd) { bd = d; bk = k; }
        }
#pragma unroll
        for (int k = 0; k < CN2; k++) if (tid == centers[k]) bk = k;
        idx2s[tid] = bk;
    }
    __syncthreads();

    if (tid == 0) {
        for (int v = 0; v < CN2; v++) cnt2[v] = 0;
        for (int i = 0; i < CN1; i++) cnt2[idx2s[i]]++;
        int slot = 0;
        for (int v = 0; v < CN2; v++) {
            srcRow[slot] = CN1 + v; cidArr[slot] = v; slot++;
            for (int i = 0; i < CN1; i++)
                if (idx2s[i] == v) { srcRow[slot] = i; cidArr[slot] = v; slot++; }
        }
        for (int v = 0; v < CN2; v++) msum[v] = 0.f;
    }
    __syncthreads();

    // ---- meta2 scatter-mean + channel sums (1024-way over ch) ----
    float ls[CN2] = {0.f, 0.f, 0.f, 0.f, 0.f, 0.f};
    for (int ch = tid; ch < C_DIM; ch += 1024) {
        float a6[CN2] = {0.f, 0.f, 0.f, 0.f, 0.f, 0.f};
        for (int r = 0; r < CN1; r++) {
            float v = M[(size_t)r * C_DIM + ch];
            int c = idx2s[r];
#pragma unroll
            for (int q = 0; q < CN2; q++) a6[q] += (c == q) ? v : 0.f;
        }
#pragma unroll
        for (int q = 0; q < CN2; q++) {
            float mv = a6[q] / ((float)cnt2[q] + 1e-6f);
            m2[q][ch] = mv;
            ls[q] += mv;
        }
    }
#pragma unroll
    for (int q = 0; q < CN2; q++) atomicAdd(&msum[q], ls[q]);
    __syncthreads();

    if (tid == 0) {
        float mean[CN2], lg[CN2];
        for (int v = 0; v < CN2; v++) mean[v] = msum[v] / (float)C_DIM;
        float mxl = -3.4e38f;
        for (int u = 0; u < CN2; u++) {
            float s = score_b[u];
            for (int v = 0; v < CN2; v++) s += mean[v] * score_w[u * CN2 + v];
            lg[u] = s;
            mxl = fmaxf(mxl, s);
        }
        float den = 0.f;
        for (int u = 0; u < CN2; u++) { lg[u] = expf(lg[u] - mxl); den += lg[u]; }
        for (int u = 0; u < CN2; u++) modu[u] = lg[u] / den;
    }
    __syncthreads();

    // ---- grouped, scaled output (1024-way over ch) ----
    float* ob = out + (size_t)t * NOUT * C_DIM;
    for (int ch = tid; ch < C_DIM; ch += 1024) {
#pragma unroll
        for (int s = 0; s < NOUT; s++) {
            int r = srcRow[s];
            float v = (r < CN1) ? M[(size_t)r * C_DIM + ch] : m2[r - CN1][ch];
            ob[(size_t)s * C_DIM + ch] = v * modu[cidArr[s]];
        }
    }
}

// ---------------------------------------------------------------------------
extern "C" void kernel_launch(void* const* d_in, const int* in_sizes, int n_in,
                              void* d_out, int out_size, void* d_ws, size_t ws_size,
                              hipStream_t stream) {
    const float* x  = (const float*)d_in[0];   // [128,256,1408]
    const float* sw = (const float*)d_in[1];   // [6,6]
    const float* sb = (const float*)d_in[2];   // [6]
    float* out = (float*)d_out;                // [128,22,1408]

    float* ws     = (float*)d_ws;
    float* dist   = ws;                                          // 8,388,608 f
    float* meta1  = dist + (size_t)T_BATCH * N_TOK * N_TOK;      // 2,883,584 f
    int*   memb   = (int*)(meta1 + (size_t)T_BATCH * CN1 * C_DIM); // 32768 i
    int*   cntg   = memb + (size_t)T_BATCH * N_TOK;              // 2048 i
    int*   offg   = cntg + T_BATCH * CN1;                        // 2048 i

    gemm_dist_tri<<<1280, 256, 0, stream>>>(x, dist);
    dpc1_fused<<<T_BATCH, 1024, 0, stream>>>(dist, memb, cntg, offg);
    merge1_kernel<<<dim3(CN1, T_BATCH), 256, 0, stream>>>(x, memb, cntg, offg, meta1);
    layer2_kernel<<<T_BATCH, 1024, 0, stream>>>(meta1, sw, sb, out);
}

// Round 7
// 448.949 us; speedup vs baseline: 1.0026x; 1.0026x over previous
//
#include <hip/hip_runtime.h>
#include <math.h>

#define T_BATCH 128
#define N_TOK   256
#define C_DIM   1408
#define CN1     16
#define KNN1    8
#define CN2     6
#define KNN2    3
#define NOUT    22   // CN2 + CN1
#define LS      44   // LDS row stride in shorts: 88B -> 16 distinct banks for
                     // 16-row fragment groups ((22r)%32 is order-16). 8B-aligned
                     // rows => fragments read as two ds_read_b64 (ld_frag).
#define NKS     44   // C_DIM / 32

typedef __attribute__((ext_vector_type(4))) short sh4;
typedef __attribute__((ext_vector_type(8))) short sh8;
typedef __attribute__((ext_vector_type(4))) float f32x4;
typedef __fp16 h2v __attribute__((ext_vector_type(2)));
typedef __fp16 h8v __attribute__((ext_vector_type(8)));

union h2u { h2v h; unsigned u; };
union frag_u { sh4 h[2]; sh8 v; };
union h8u { sh8 s; h8v h; };

// 8B-aligned 16B fragment load: two b64 reads (LS=44 rows are 8B-aligned).
__device__ inline h8v ld_frag_h(const short* p) {
    frag_u u;
    u.h[0] = *(const sh4*)p;
    u.h[1] = *(const sh4*)(p + 4);
    h8u o; o.s = u.v;
    return o.h;
}

// f16 two-term split of a float4: hi = rtz-f16 of f, lo = rtz-f16 of (f - hi).
__device__ inline void cvt4_f16(const float4 f, uint2& vh, uint2& vl) {
    h2v h0 = __builtin_amdgcn_cvt_pkrtz(f.x, f.y);
    h2v h1 = __builtin_amdgcn_cvt_pkrtz(f.z, f.w);
    float l0 = f.x - (float)h0[0];
    float l1 = f.y - (float)h0[1];
    float l2 = f.z - (float)h1[0];
    float l3 = f.w - (float)h1[1];
    h2v g0 = __builtin_amdgcn_cvt_pkrtz(l0, l1);
    h2v g1 = __builtin_amdgcn_cvt_pkrtz(l2, l3);
    h2u a0, a1, b0, b1;
    a0.h = h0; a1.h = h1; b0.h = g0; b1.h = g1;
    vh.x = a0.u; vh.y = a1.u;
    vl.x = b0.u; vl.y = b1.u;
}

// branchless insert of v into ascending 8-list m (keeps 8 smallest)
#define INS8(m, v) {                                   \
    float _x = (v);                                    \
    _Pragma("unroll")                                  \
    for (int _q = 0; _q < 8; _q++) {                   \
        float _lo = fminf(m[_q], _x);                  \
        _x = fmaxf(m[_q], _x);                         \
        m[_q] = _lo;                                   \
    }                                                  \
}

// ---------------------------------------------------------------------------
// Kernel A: dist via f16x2-split MFMA, 64x64 tiles, upper-tri pairs only.
// Grid 1280 (XCD-swizzled, 10 blocks/batch), 256 thr, 4 blocks/CU so other
// blocks' waves hide each block's barriers. LS=44 (conflict-free fragment
// reads, v1/v2-proven). Coalesced staging (8 lanes = 128B contiguous row
// chunk). f16x2 convert. T14: k+1 loads issue before ds_read/MFMA.
// ---------------------------------------------------------------------------
__global__ __launch_bounds__(256, 4) void gemm_dist_tri(const float* __restrict__ x,
                                                        float* __restrict__ dist) {
    const int id = blockIdx.x;
    const int r  = id & 7;
    const int q8 = id >> 3;          // 0..159
    const int p  = q8 % 10;
    const int tt = q8 / 10;          // 0..15
    const int t  = tt * 8 + r;
    const int bi = (p < 4) ? 0 : (p < 7) ? 1 : (p < 9) ? 2 : 3;
    const int bj = (p < 4) ? p : (p < 7) ? p - 3 : (p < 9) ? p - 5 : 3;
    const int i0 = bi * 64, j0 = bj * 64;
    const bool diag = (bi == bj);
    const float* X = x + (size_t)t * N_TOK * C_DIM;

    __shared__ short Ahi[64 * LS], Alo[64 * LS], Bhi[64 * LS], Blo[64 * LS];
    __shared__ float nrA[64][8], nrB[64][8];
    __shared__ float snA[64], snB[64];

    const int tid  = threadIdx.x;
    const int wave = tid >> 6;       // 0..3
    const int lane = tid & 63;
    const int qr   = wave >> 1;
    const int qc   = wave & 1;
    const int rA   = tid >> 3;       // 0..31 (staging row; also +32)
    const int c8   = tid & 7;        // float4 slot within 32-float K-chunk
    const int fr   = lane & 15;
    const int fq   = lane >> 4;

    const short* BhiS = diag ? Ahi : Bhi;
    const short* BloS = diag ? Alo : Blo;

    f32x4 acc[2][2];
#pragma unroll
    for (int a = 0; a < 2; a++)
#pragma unroll
        for (int b = 0; b < 2; b++) acc[a][b] = (f32x4){0.f, 0.f, 0.f, 0.f};

    const float* A0 = X + (size_t)(i0 + rA) * C_DIM + c8 * 4;
    const float* A1 = X + (size_t)(i0 + rA + 32) * C_DIM + c8 * 4;
    const float* B0 = X + (size_t)(j0 + rA) * C_DIM + c8 * 4;
    const float* B1 = X + (size_t)(j0 + rA + 32) * C_DIM + c8 * 4;
    float nA0 = 0.f, nA1 = 0.f, nB0 = 0.f, nB1 = 0.f;

    // ---- prologue: preload K-chunk 0 ----
    float4 fa0 = *(const float4*)(A0);
    float4 fa1 = *(const float4*)(A1);
    float4 fb0 = {0.f, 0.f, 0.f, 0.f}, fb1 = {0.f, 0.f, 0.f, 0.f};
    if (!diag) {
        fb0 = *(const float4*)(B0);
        fb1 = *(const float4*)(B1);
    }

    for (int ks = 0; ks < NKS; ks++) {
        // convert current regs
        uint2 ah0, al0, ah1, al1, bh0, bl0, bh1, bl1;
        nA0 += fa0.x * fa0.x + fa0.y * fa0.y + fa0.z * fa0.z + fa0.w * fa0.w;
        nA1 += fa1.x * fa1.x + fa1.y * fa1.y + fa1.z * fa1.z + fa1.w * fa1.w;
        cvt4_f16(fa0, ah0, al0);
        cvt4_f16(fa1, ah1, al1);
        if (!diag) {
            nB0 += fb0.x * fb0.x + fb0.y * fb0.y + fb0.z * fb0.z + fb0.w * fb0.w;
            nB1 += fb1.x * fb1.x + fb1.y * fb1.y + fb1.z * fb1.z + fb1.w * fb1.w;
            cvt4_f16(fb0, bh0, bl0);
            cvt4_f16(fb1, bh1, bl1);
        }
        __syncthreads();   // previous K-step's reads complete
        *(uint2*)&Ahi[rA * LS + c8 * 4]        = ah0;
        *(uint2*)&Alo[rA * LS + c8 * 4]        = al0;
        *(uint2*)&Ahi[(rA + 32) * LS + c8 * 4] = ah1;
        *(uint2*)&Alo[(rA + 32) * LS + c8 * 4] = al1;
        if (!diag) {
            *(uint2*)&Bhi[rA * LS + c8 * 4]        = bh0;
            *(uint2*)&Blo[rA * LS + c8 * 4]        = bl0;
            *(uint2*)&Bhi[(rA + 32) * LS + c8 * 4] = bh1;
            *(uint2*)&Blo[(rA + 32) * LS + c8 * 4] = bl1;
        }
        __syncthreads();   // panel visible

        // T14: issue next K-chunk's loads before ds_read/MFMA
        const int k1 = (ks + 1) * 32;
        if (k1 < C_DIM) {
            fa0 = *(const float4*)(A0 + k1);
            fa1 = *(const float4*)(A1 + k1);
            if (!diag) {
                fb0 = *(const float4*)(B0 + k1);
                fb1 = *(const float4*)(B1 + k1);
            }
        }

        h8v fAh[2], fAl[2], fBh[2], fBl[2];
#pragma unroll
        for (int mt = 0; mt < 2; mt++) {
            int ro = (qr * 32 + mt * 16 + fr) * LS + fq * 8;
            fAh[mt] = ld_frag_h(&Ahi[ro]);
            fAl[mt] = ld_frag_h(&Alo[ro]);
            int co = (qc * 32 + mt * 16 + fr) * LS + fq * 8;
            fBh[mt] = ld_frag_h(&BhiS[co]);
            fBl[mt] = ld_frag_h(&BloS[co]);
        }
#pragma unroll
        for (int mt = 0; mt < 2; mt++)
#pragma unroll
            for (int nt = 0; nt < 2; nt++) {
                acc[mt][nt] = __builtin_amdgcn_mfma_f32_16x16x32_f16(fAh[mt], fBh[nt], acc[mt][nt], 0, 0, 0);
                acc[mt][nt] = __builtin_amdgcn_mfma_f32_16x16x32_f16(fAh[mt], fBl[nt], acc[mt][nt], 0, 0, 0);
                acc[mt][nt] = __builtin_amdgcn_mfma_f32_16x16x32_f16(fAl[mt], fBh[nt], acc[mt][nt], 0, 0, 0);
            }
    }

    // ---- row norms ----
    nrA[rA][c8] = nA0;
    nrA[rA + 32][c8] = nA1;
    nrB[rA][c8] = diag ? nA0 : nB0;
    nrB[rA + 32][c8] = diag ? nA1 : nB1;
    __syncthreads();
    if (tid < 64) {
        float sa = 0.f, sb = 0.f;
#pragma unroll
        for (int c = 0; c < 8; c++) { sa += nrA[tid][c]; sb += nrB[tid][c]; }
        snA[tid] = sa;
        snB[tid] = sb;
    }
    __syncthreads();

    const float inv_sqrtC = 1.0f / sqrtf((float)C_DIM);
    float* Dt = dist + (size_t)t * N_TOK * N_TOK;
#pragma unroll
    for (int mt = 0; mt < 2; mt++)
#pragma unroll
        for (int nt = 0; nt < 2; nt++) {
            int jl = qc * 32 + nt * 16 + fr;
            int jg = j0 + jl;
            float sqj = snB[jl];
            int il0 = qr * 32 + mt * 16 + fq * 4;
            float vv[4];
#pragma unroll
            for (int rr = 0; rr < 4; rr++) {
                int ig = i0 + il0 + rr;
                float d2 = snA[il0 + rr] + sqj - 2.0f * acc[mt][nt][rr];
                float v = (ig == jg) ? 0.0f : sqrtf(fmaxf(d2, 0.0f)) * inv_sqrtC;
                Dt[(size_t)ig * N_TOK + jg] = v;
                vv[rr] = v;
            }
            if (!diag) {
                float4 o; o.x = vv[0]; o.y = vv[1]; o.z = vv[2]; o.w = vv[3];
                *(float4*)&Dt[(size_t)jg * N_TOK + i0 + il0] = o;
            }
        }
}

// ---------------------------------------------------------------------------
// Kernel B: fused layer-1 DPC. 1024 threads/block, one block per batch.
// 4 threads per column (64-row quarter scans), 2 chains each, LDS merge.
// ---------------------------------------------------------------------------
__global__ __launch_bounds__(1024) void dpc1_fused(const float* __restrict__ dist,
                                                   int* __restrict__ memb,
                                                   int* __restrict__ cntg,
                                                   int* __restrict__ offg) {
    const int t    = blockIdx.x;
    const int tid  = threadIdx.x;    // 0..1023
    const int col  = tid & 255;
    const int h    = tid >> 8;       // row quarter 0..3
    const int lane = tid & 63;
    const int wid  = tid >> 6;       // 0..15
    const float* D = dist + (size_t)t * N_TOK * N_TOK;

    __shared__ float dens_s[N_TOK];
    __shared__ float lists[KNN1][1024];
    __shared__ float red[1024];
    __shared__ float rmax16[16];
    __shared__ unsigned long long wred[16];
    __shared__ int centers[CN1];
    __shared__ int bks[N_TOK];
    __shared__ int cnt_s[CN1], off_s[CN1];

    // ---- pass 1: 8 smallest of this quarter-column, 2 chains ----
    float c0[8], c1[8];
#pragma unroll
    for (int q = 0; q < 8; q++) { c0[q] = 3.4e38f; c1[q] = 3.4e38f; }
    float mx = 0.f;
    const float* base = D + (size_t)(h * 64) * N_TOK + col;
    for (int jj = 0; jj < 64; jj += 2) {
        float d0 = base[(size_t)(jj + 0) * N_TOK];
        float d1 = base[(size_t)(jj + 1) * N_TOK];
        mx = fmaxf(mx, fmaxf(d0, d1));
        INS8(c0, d0); INS8(c1, d1);
    }
#pragma unroll
    for (int q = 0; q < 8; q++) { INS8(c0, c1[q]); }
#pragma unroll
    for (int q = 0; q < 8; q++) lists[q][tid] = c0[q];
    // dmax: wave shuffle-reduce, then 16-entry LDS
#pragma unroll
    for (int off = 32; off > 0; off >>= 1) mx = fmaxf(mx, __shfl_xor(mx, off));
    if (lane == 0) rmax16[wid] = mx;
    __syncthreads();
    float dmax = rmax16[0];
#pragma unroll
    for (int w = 1; w < 16; w++) dmax = fmaxf(dmax, rmax16[w]);

    if (h == 0) {
#pragma unroll
        for (int s = 1; s < 4; s++)
#pragma unroll
            for (int q = 0; q < 8; q++) { float v = lists[q][col + s * 256]; INS8(c0, v); }
        float s2 = 0.f;
#pragma unroll
        for (int q = 0; q < 8; q++) s2 += c0[q] * c0[q];
        dens_s[col] = expf(-s2 / (float)KNN1);
    }
    __syncthreads();
    const float dens = dens_s[col];

    // ---- pass 2: parent distance over this quarter, 2 chains ----
    float p0 = dmax, p1 = dmax;
    const float* dsh = dens_s + h * 64;
    for (int jj = 0; jj < 64; jj += 2) {
        float d0 = base[(size_t)(jj + 0) * N_TOK];
        float d1 = base[(size_t)(jj + 1) * N_TOK];
        p0 = (dsh[jj + 0] > dens) ? fminf(p0, d0) : p0;
        p1 = (dsh[jj + 1] > dens) ? fminf(p1, d1) : p1;
    }
    red[tid] = fminf(p0, p1);
    __syncthreads();
    float score = 0.f;
    if (h == 0)
        score = fminf(fminf(red[col], red[col + 256]),
                      fminf(red[col + 512], red[col + 768])) * dens;

    // ---- top-16 (desc, ties -> lowest index) ----
    unsigned long long key = 0;
    if (h == 0)
        key = ((unsigned long long)__float_as_uint(score) << 32) | (unsigned)(65535 - col);
    for (int k = 0; k < CN1; k++) {
        unsigned long long mm = key;
#pragma unroll
        for (int off = 32; off > 0; off >>= 1) {
            unsigned long long o = __shfl_xor(mm, off);
            mm = (o > mm) ? o : mm;
        }
        if (lane == 0) wred[wid] = mm;
        __syncthreads();
        unsigned long long b = wred[0];
#pragma unroll
        for (int w = 1; w < 16; w++) b = (wred[w] > b) ? wred[w] : b;
        int idx = 65535 - (int)(b & 0xFFFFull);
        if (tid == 0) centers[k] = idx;
        if (tid == idx) key = 0;
        __syncthreads();
    }

    // ---- assign + member lists (h==0 threads; barriers unconditional) ----
    int bk = 0;
    if (h == 0) {
        float bd = 3.4e38f;
#pragma unroll
        for (int k = 0; k < CN1; k++) {
            float d = D[(size_t)centers[k] * N_TOK + col];
            if (d < bd) { bd = d; bk = k; }
        }
#pragma unroll
        for (int k = 0; k < CN1; k++) if (col == centers[k]) bk = k;
        bks[col] = bk;
    }
    __syncthreads();
    if (tid < CN1) {
        int c = 0;
        for (int j = 0; j < N_TOK; j++) c += (bks[j] == tid);
        cnt_s[tid] = c;
    }
    __syncthreads();
    if (tid == 0) {
        int o = 0;
        for (int q = 0; q < CN1; q++) { off_s[q] = o; o += cnt_s[q]; }
    }
    __syncthreads();
    if (h == 0) {
        int rank = 0;
        for (int j = 0; j < col; j++) rank += (bks[j] == bk);
        memb[t * N_TOK + off_s[bk] + rank] = col;
    }
    if (tid < CN1) {
        cntg[t * CN1 + tid] = cnt_s[tid];
        offg[t * CN1 + tid] = off_s[tid];
    }
}

// ---------------------------------------------------------------------------
// Kernel C: merge1 via member lists, member loop unrolled x4 (4 independent
// row streams in flight; summation order preserved).
// ---------------------------------------------------------------------------
__global__ __launch_bounds__(256) void merge1_kernel(const float* __restrict__ x,
                                                     const int* __restrict__ memb,
                                                     const int* __restrict__ cntg,
                                                     const int* __restrict__ offg,
                                                     float* __restrict__ meta1) {
    const int q   = blockIdx.x;
    const int t   = blockIdx.y;
    const int tid = threadIdx.x;
    const int n    = cntg[t * CN1 + q];
    const int base = t * N_TOK + offg[t * CN1 + q];
    const int c0 = tid, c1 = tid + 256;
    const bool act1 = (c1 < C_DIM / 4);
    const float4* xb = (const float4*)(x + (size_t)t * N_TOK * C_DIM);
    const int stride4 = C_DIM / 4;

    float4 s0 = {0.f, 0.f, 0.f, 0.f};
    float4 s1 = {0.f, 0.f, 0.f, 0.f};
    int m = 0;
    for (; m + 4 <= n; m += 4) {
        int r0 = memb[base + m + 0];
        int r1 = memb[base + m + 1];
        int r2 = memb[base + m + 2];
        int r3 = memb[base + m + 3];
        float4 a0 = xb[(size_t)r0 * stride4 + c0];
        float4 a1 = xb[(size_t)r1 * stride4 + c0];
        float4 a2 = xb[(size_t)r2 * stride4 + c0];
        float4 a3 = xb[(size_t)r3 * stride4 + c0];
        s0.x += a0.x; s0.y += a0.y; s0.z += a0.z; s0.w += a0.w;
        s0.x += a1.x; s0.y += a1.y; s0.z += a1.z; s0.w += a1.w;
        s0.x += a2.x; s0.y += a2.y; s0.z += a2.z; s0.w += a2.w;
        s0.x += a3.x; s0.y += a3.y; s0.z += a3.z; s0.w += a3.w;
        if (act1) {
            float4 b0 = xb[(size_t)r0 * stride4 + c1];
            float4 b1 = xb[(size_t)r1 * stride4 + c1];
            float4 b2 = xb[(size_t)r2 * stride4 + c1];
            float4 b3 = xb[(size_t)r3 * stride4 + c1];
            s1.x += b0.x; s1.y += b0.y; s1.z += b0.z; s1.w += b0.w;
            s1.x += b1.x; s1.y += b1.y; s1.z += b1.z; s1.w += b1.w;
            s1.x += b2.x; s1.y += b2.y; s1.z += b2.z; s1.w += b2.w;
            s1.x += b3.x; s1.y += b3.y; s1.z += b3.z; s1.w += b3.w;
        }
    }
    for (; m < n; m++) {
        int r0 = memb[base + m];
        float4 a0 = xb[(size_t)r0 * stride4 + c0];
        s0.x += a0.x; s0.y += a0.y; s0.z += a0.z; s0.w += a0.w;
        if (act1) {
            float4 b0 = xb[(size_t)r0 * stride4 + c1];
            s1.x += b0.x; s1.y += b0.y; s1.z += b0.z; s1.w += b0.w;
        }
    }
    float w = 1.0f / ((float)n + 1e-6f);
    float4* mr = (float4*)(meta1 + ((size_t)t * CN1 + q) * C_DIM);
    float4 o0; o0.x = s0.x * w; o0.y = s0.y * w; o0.z = s0.z * w; o0.w = s0.w * w;
    mr[c0] = o0;
    if (act1) {
        float4 o1; o1.x = s1.x * w; o1.y = s1.y * w; o1.z = s1.z * w; o1.w = s1.w * w;
        mr[c1] = o1;
    }
}

// ---------------------------------------------------------------------------
// Kernel DE: layer-2 DPC + merge2 + modulation + grouped output.
// 1024 threads per block, one block per batch.
// ---------------------------------------------------------------------------
__global__ __launch_bounds__(1024) void layer2_kernel(const float* __restrict__ meta1,
                                                      const float* __restrict__ score_w,
                                                      const float* __restrict__ score_b,
                                                      float* __restrict__ out) {
    const int t   = blockIdx.x;
    const int tid = threadIdx.x;   // 0..1023
    const float* M = meta1 + (size_t)t * CN1 * C_DIM;

    __shared__ float buf[CN1][132];
    __shared__ float d2s[CN1][CN1];
    __shared__ float m2[CN2][C_DIM];
    __shared__ float dens[CN1], scor[CN1], nrm[CN1], rmx[CN1];
    __shared__ int   centers[CN2], idx2s[CN1], cnt2[CN2];
    __shared__ float modu[CN2], msum[CN2];
    __shared__ int   srcRow[NOUT], cidArr[NOUT];
    __shared__ float dmax_sh;

    const int ti = (tid < 256) ? (tid >> 4) : 0;
    const int tj = tid & 15;

    // ---- pairwise dots (threads 0-255 own one (i,j) pair; all stage) ----
    float acc = 0.f;
    for (int c0 = 0; c0 < C_DIM; c0 += 128) {
        for (int e = tid; e < CN1 * 128; e += 1024) {
            int r = e >> 7, c = e & 127;
            buf[r][c] = M[(size_t)r * C_DIM + c0 + c];
        }
        __syncthreads();
        if (tid < 256) {
#pragma unroll
            for (int cc = 0; cc < 128; cc += 4) {
                float4 a = *(const float4*)&buf[ti][cc];
                float4 b = *(const float4*)&buf[tj][cc];
                acc += a.x * b.x + a.y * b.y + a.z * b.z + a.w * b.w;
            }
        }
        __syncthreads();
    }
    if (tid < 256 && ti == tj) nrm[ti] = acc;
    __syncthreads();

    const float inv_sqrtC = 1.0f / sqrtf((float)C_DIM);
    if (tid < 256) {
        float d2 = nrm[ti] + nrm[tj] - 2.f * acc;
        d2s[ti][tj] = sqrtf(fmaxf(d2, 0.f)) * inv_sqrtC;
    }
    __syncthreads();

    if (tid < CN1) {
        float m0 = 3.4e38f, m1 = 3.4e38f, m2v = 3.4e38f, mx = 0.f;
        for (int j = 0; j < CN1; j++) {
            float d = d2s[tid][j];
            mx = fmaxf(mx, d);
            if (d < m2v) {
                m2v = d;
                if (m2v < m1) { float tmp = m2v; m2v = m1; m1 = tmp; }
                if (m1 < m0)  { float tmp = m1;  m1 = m0;  m0 = tmp; }
            }
        }
        dens[tid] = expf(-(m0 * m0 + m1 * m1 + m2v * m2v) / (float)KNN2);
        rmx[tid] = mx;
    }
    __syncthreads();
    if (tid == 0) {
        float g = 0.f;
        for (int j = 0; j < CN1; j++) g = fmaxf(g, rmx[j]);
        dmax_sh = g;
    }
    __syncthreads();

    if (tid < CN1) {
        float di = dens[tid];
        float pd = dmax_sh;
        for (int j = 0; j < CN1; j++)
            if (dens[j] > di) pd = fminf(pd, d2s[tid][j]);
        scor[tid] = pd * di;
    }
    __syncthreads();

    if (tid == 0) {
        for (int k = 0; k < CN2; k++) {
            float best = -3.4e38f; int bi = 0;
            for (int j = 0; j < CN1; j++)
                if (scor[j] > best) { best = scor[j]; bi = j; }
            centers[k] = bi;
            scor[bi] = -3.4e38f;
        }
    }
    __syncthreads();

    if (tid < CN1) {
        float bd = 3.4e38f; int bk = 0;
#pragma unroll
        for (int k = 0; k < CN2; k++) {
            float d = d2s[centers[k]][tid];
            if (d < bd) { bd = d; bk = k; }
        }
#pragma unroll
        for (int k = 0; k < CN2; k++) if (tid == centers[k]) bk = k;
        idx2s[tid] = bk;
    }
    __syncthreads();

    if (tid == 0) {
        for (int v = 0; v < CN2; v++) cnt2[v] = 0;
        for (int i = 0; i < CN1; i++) cnt2[idx2s[i]]++;
        int slot = 0;
        for (int v = 0; v < CN2; v++) {
            srcRow[slot] = CN1 + v; cidArr[slot] = v; slot++;
            for (int i = 0; i < CN1; i++)
                if (idx2s[i] == v) { srcRow[slot] = i; cidArr[slot] = v; slot++; }
        }
        for (int v = 0; v < CN2; v++) msum[v] = 0.f;
    }
    __syncthreads();

    // ---- meta2 scatter-mean + channel sums (1024-way over ch) ----
    float ls[CN2] = {0.f, 0.f, 0.f, 0.f, 0.f, 0.f};
    for (int ch = tid; ch < C_DIM; ch += 1024) {
        float a6[CN2] = {0.f, 0.f, 0.f, 0.f, 0.f, 0.f};
        for (int r = 0; r < CN1; r++) {
            float v = M[(size_t)r * C_DIM + ch];
            int c = idx2s[r];
#pragma unroll
            for (int q = 0; q < CN2; q++) a6[q] += (c == q) ? v : 0.f;
        }
#pragma unroll
        for (int q = 0; q < CN2; q++) {
            float mv = a6[q] / ((float)cnt2[q] + 1e-6f);
            m2[q][ch] = mv;
            ls[q] += mv;
        }
    }
#pragma unroll
    for (int q = 0; q < CN2; q++) atomicAdd(&msum[q], ls[q]);
    __syncthreads();

    if (tid == 0) {
        float mean[CN2], lg[CN2];
        for (int v = 0; v < CN2; v++) mean[v] = msum[v] / (float)C_DIM;
        float mxl = -3.4e38f;
        for (int u = 0; u < CN2; u++) {
            float s = score_b[u];
            for (int v = 0; v < CN2; v++) s += mean[v] * score_w[u * CN2 + v];
            lg[u] = s;
            mxl = fmaxf(mxl, s);
        }
        float den = 0.f;
        for (int u = 0; u < CN2; u++) { lg[u] = expf(lg[u] - mxl); den += lg[u]; }
        for (int u = 0; u < CN2; u++) modu[u] = lg[u] / den;
    }
    __syncthreads();

    // ---- grouped, scaled output (1024-way over ch) ----
    float* ob = out + (size_t)t * NOUT * C_DIM;
    for (int ch = tid; ch < C_DIM; ch += 1024) {
#pragma unroll
        for (int s = 0; s < NOUT; s++) {
            int r = srcRow[s];
            float v = (r < CN1) ? M[(size_t)r * C_DIM + ch] : m2[r - CN1][ch];
            ob[(size_t)s * C_DIM + ch] = v * modu[cidArr[s]];
        }
    }
}

// ---------------------------------------------------------------------------
extern "C" void kernel_launch(void* const* d_in, const int* in_sizes, int n_in,
                              void* d_out, int out_size, void* d_ws, size_t ws_size,
                              hipStream_t stream) {
    const float* x  = (const float*)d_in[0];   // [128,256,1408]
    const float* sw = (const float*)d_in[1];   // [6,6]
    const float* sb = (const float*)d_in[2];   // [6]
    float* out = (float*)d_out;                // [128,22,1408]

    float* ws     = (float*)d_ws;
    float* dist   = ws;                                          // 8,388,608 f
    float* meta1  = dist + (size_t)T_BATCH * N_TOK * N_TOK;      // 2,883,584 f
    int*   memb   = (int*)(meta1 + (size_t)T_BATCH * CN1 * C_DIM); // 32768 i
    int*   cntg   = memb + (size_t)T_BATCH * N_TOK;              // 2048 i
    int*   offg   = cntg + T_BATCH * CN1;                        // 2048 i

    gemm_dist_tri<<<1280, 256, 0, stream>>>(x, dist);
    dpc1_fused<<<T_BATCH, 1024, 0, stream>>>(dist, memb, cntg, offg);
    merge1_kernel<<<dim3(CN1, T_BATCH), 256, 0, stream>>>(x, memb, cntg, offg, meta1);
    layer2_kernel<<<T_BATCH, 1024, 0, stream>>>(meta1, sw, sb, out);
}

// Round 8
// 419.314 us; speedup vs baseline: 1.0735x; 1.0707x over previous
//
#include <hip/hip_runtime.h>
#include <math.h>

#define T_BATCH 128
#define N_TOK   256
#define C_DIM   1408
#define CN1     16
#define KNN1    8
#define CN2     6
#define KNN2    3
#define NOUT    22   // CN2 + CN1
#define LS      44   // LDS row stride in shorts (22 words), 8B-aligned rows

typedef __attribute__((ext_vector_type(4))) short sh4;
typedef __attribute__((ext_vector_type(8))) short sh8;
typedef __attribute__((ext_vector_type(4))) float f32x4;

union frag_u { sh4 h[2]; sh8 v; };

__device__ inline sh8 ld_frag(const short* p) {
    frag_u u;
    u.h[0] = *(const sh4*)p;
    u.h[1] = *(const sh4*)(p + 4);
    return u.v;
}

// truncation split of a PAIR of fp32 -> packed bf16 hi pair + RNE bf16 lo pair.
__device__ inline void split2(float v0, float v1, unsigned& hip, unsigned& lop) {
    unsigned u0 = __float_as_uint(v0);
    unsigned u1 = __float_as_uint(v1);
    hip = (u0 >> 16) | (u1 & 0xFFFF0000u);
    float l0 = v0 - __uint_as_float(u0 & 0xFFFF0000u);
    float l1 = v1 - __uint_as_float(u1 & 0xFFFF0000u);
    unsigned w0 = __float_as_uint(l0);
    unsigned w1 = __float_as_uint(l1);
    w0 = w0 + 0x7FFFu + ((w0 >> 16) & 1u);
    w1 = w1 + 0x7FFFu + ((w1 >> 16) & 1u);
    lop = (w0 >> 16) | (w1 & 0xFFFF0000u);
}

// branchless insert of v into ascending 8-list m (keeps 8 smallest)
#define INS8(m, v) {                                   \
    float _x = (v);                                    \
    _Pragma("unroll")                                  \
    for (int _q = 0; _q < 8; _q++) {                   \
        float _lo = fminf(m[_q], _x);                  \
        _x = fmaxf(m[_q], _x);                         \
        m[_q] = _lo;                                   \
    }                                                  \
}

// ---------------------------------------------------------------------------
// Kernel A: dist via bf16x3 MFMA, 64x64 tiles, upper-tri pairs only.
// EXACT r0 configuration (best measured: total 421.8, gemm <=109):
// grid 1280 XCD-swizzled, 256 thr, 4 blocks/CU, LS=44, scattered staging,
// T14 prefetch. All later variants (128x256 panel, f16 convert, coalesced
// staging, dbuf, LS=40) measured SLOWER (116-133 us) - do not reapply.
// ---------------------------------------------------------------------------
__global__ __launch_bounds__(256, 4) void gemm_dist_sym(const float* __restrict__ x,
                                                        float* __restrict__ dist) {
    const int id = blockIdx.x;
    const int r  = id & 7;
    const int q8 = id >> 3;          // 0..159
    const int p  = q8 % 10;
    const int tt = q8 / 10;          // 0..15
    const int t  = tt * 8 + r;
    const int bi = (p < 4) ? 0 : (p < 7) ? 1 : (p < 9) ? 2 : 3;
    const int bj = (p < 4) ? p : (p < 7) ? p - 3 : (p < 9) ? p - 5 : 3;
    const int i0 = bi * 64, j0 = bj * 64;
    const bool diag = (bi == bj);
    const float* X = x + (size_t)t * N_TOK * C_DIM;

    __shared__ short Ahi[64 * LS], Alo[64 * LS], Bhi[64 * LS], Blo[64 * LS];
    __shared__ float nred[512];
    __shared__ float snA[64], snB[64];

    const int tid  = threadIdx.x;
    const int wave = tid >> 6;
    const int lane = tid & 63;
    const int qr   = wave >> 1;
    const int qc   = wave & 1;
    const int srow = tid >> 2;
    const int sq   = tid & 3;
    const int fr   = lane & 15;
    const int fq   = lane >> 4;

    const short* BhiS = diag ? Ahi : Bhi;
    const short* BloS = diag ? Alo : Blo;

    f32x4 acc[2][2];
#pragma unroll
    for (int a = 0; a < 2; a++)
#pragma unroll
        for (int b = 0; b < 2; b++) acc[a][b] = (f32x4){0.f, 0.f, 0.f, 0.f};

    const float* Arow = X + (size_t)(i0 + srow) * C_DIM + sq * 8;
    const float* Brow = X + (size_t)(j0 + srow) * C_DIM + sq * 8;
    float nA = 0.f, nB = 0.f;

    // --- prologue: preload K-step 0 into registers ---
    float4 a0 = *(const float4*)(Arow + 0);
    float4 a1 = *(const float4*)(Arow + 4);
    float4 b0 = {0.f, 0.f, 0.f, 0.f}, b1 = {0.f, 0.f, 0.f, 0.f};
    if (!diag) {
        b0 = *(const float4*)(Brow + 0);
        b1 = *(const float4*)(Brow + 4);
    }

    for (int k0 = 0; k0 < C_DIM; k0 += 32) {
        float av[8], bv[8];
        av[0] = a0.x; av[1] = a0.y; av[2] = a0.z; av[3] = a0.w;
        av[4] = a1.x; av[5] = a1.y; av[6] = a1.z; av[7] = a1.w;
#pragma unroll
        for (int e = 0; e < 8; e++) nA += av[e] * av[e];
        unsigned ah[4], al[4], bh[4], bl[4];
#pragma unroll
        for (int q = 0; q < 4; q++) split2(av[2 * q], av[2 * q + 1], ah[q], al[q]);
        if (!diag) {
            bv[0] = b0.x; bv[1] = b0.y; bv[2] = b0.z; bv[3] = b0.w;
            bv[4] = b1.x; bv[5] = b1.y; bv[6] = b1.z; bv[7] = b1.w;
#pragma unroll
            for (int e = 0; e < 8; e++) nB += bv[e] * bv[e];
#pragma unroll
            for (int q = 0; q < 4; q++) split2(bv[2 * q], bv[2 * q + 1], bh[q], bl[q]);
        }
        __syncthreads();
        {
            unsigned* AH = (unsigned*)&Ahi[srow * LS + sq * 8];
            unsigned* AL = (unsigned*)&Alo[srow * LS + sq * 8];
#pragma unroll
            for (int q = 0; q < 4; q++) { AH[q] = ah[q]; AL[q] = al[q]; }
            if (!diag) {
                unsigned* BH = (unsigned*)&Bhi[srow * LS + sq * 8];
                unsigned* BL = (unsigned*)&Blo[srow * LS + sq * 8];
#pragma unroll
                for (int q = 0; q < 4; q++) { BH[q] = bh[q]; BL[q] = bl[q]; }
            }
        }
        __syncthreads();

        // --- T14: issue next K-step's global loads before ds_read/MFMA ---
        const int k1 = k0 + 32;
        if (k1 < C_DIM) {
            a0 = *(const float4*)(Arow + k1);
            a1 = *(const float4*)(Arow + k1 + 4);
            if (!diag) {
                b0 = *(const float4*)(Brow + k1);
                b1 = *(const float4*)(Brow + k1 + 4);
            }
        }

        sh8 fAh[2], fAl[2], fBh[2], fBl[2];
#pragma unroll
        for (int mt = 0; mt < 2; mt++) {
            int ro = (qr * 32 + mt * 16 + fr) * LS + fq * 8;
            fAh[mt] = ld_frag(&Ahi[ro]);
            fAl[mt] = ld_frag(&Alo[ro]);
            int co = (qc * 32 + mt * 16 + fr) * LS + fq * 8;
            fBh[mt] = ld_frag(&BhiS[co]);
            fBl[mt] = ld_frag(&BloS[co]);
        }
#pragma unroll
        for (int mt = 0; mt < 2; mt++)
#pragma unroll
            for (int nt = 0; nt < 2; nt++) {
                acc[mt][nt] = __builtin_amdgcn_mfma_f32_16x16x32_bf16(fAh[mt], fBh[nt], acc[mt][nt], 0, 0, 0);
                acc[mt][nt] = __builtin_amdgcn_mfma_f32_16x16x32_bf16(fAh[mt], fBl[nt], acc[mt][nt], 0, 0, 0);
                acc[mt][nt] = __builtin_amdgcn_mfma_f32_16x16x32_bf16(fAl[mt], fBh[nt], acc[mt][nt], 0, 0, 0);
            }
    }

    nred[tid] = nA;
    nred[256 + tid] = diag ? nA : nB;
    __syncthreads();
    if (tid < 64) {
        snA[tid] = nred[4 * tid] + nred[4 * tid + 1] + nred[4 * tid + 2] + nred[4 * tid + 3];
        snB[tid] = nred[256 + 4 * tid] + nred[256 + 4 * tid + 1]
                 + nred[256 + 4 * tid + 2] + nred[256 + 4 * tid + 3];
    }
    __syncthreads();

    const float inv_sqrtC = 1.0f / sqrtf((float)C_DIM);
    float* Dt = dist + (size_t)t * N_TOK * N_TOK;
#pragma unroll
    for (int mt = 0; mt < 2; mt++)
#pragma unroll
        for (int nt = 0; nt < 2; nt++) {
            int jl = qc * 32 + nt * 16 + fr;
            int jg = j0 + jl;
            float sqj = snB[jl];
            int il0 = qr * 32 + mt * 16 + fq * 4;
            float vv[4];
#pragma unroll
            for (int rr = 0; rr < 4; rr++) {
                int ig = i0 + il0 + rr;
                float d2 = snA[il0 + rr] + sqj - 2.0f * acc[mt][nt][rr];
                float v = (ig == jg) ? 0.0f : sqrtf(fmaxf(d2, 0.0f)) * inv_sqrtC;
                Dt[(size_t)ig * N_TOK + jg] = v;
                vv[rr] = v;
            }
            if (!diag) {
                float4 o; o.x = vv[0]; o.y = vv[1]; o.z = vv[2]; o.w = vv[3];
                *(float4*)&Dt[(size_t)jg * N_TOK + i0 + il0] = o;
            }
        }
}

// ---------------------------------------------------------------------------
// Kernel B: fused layer-1 DPC. 1024 threads/block, one block per batch.
// 4 threads per column (64-row quarter scans), 2 chains each, LDS merge.
// ---------------------------------------------------------------------------
__global__ __launch_bounds__(1024) void dpc1_fused(const float* __restrict__ dist,
                                                   int* __restrict__ memb,
                                                   int* __restrict__ cntg,
                                                   int* __restrict__ offg) {
    const int t    = blockIdx.x;
    const int tid  = threadIdx.x;    // 0..1023
    const int col  = tid & 255;
    const int h    = tid >> 8;       // row quarter 0..3
    const int lane = tid & 63;
    const int wid  = tid >> 6;       // 0..15
    const float* D = dist + (size_t)t * N_TOK * N_TOK;

    __shared__ float dens_s[N_TOK];
    __shared__ float lists[KNN1][1024];
    __shared__ float red[1024];
    __shared__ float rmax16[16];
    __shared__ unsigned long long wred[16];
    __shared__ int centers[CN1];
    __shared__ int bks[N_TOK];
    __shared__ int cnt_s[CN1], off_s[CN1];

    // ---- pass 1: 8 smallest of this quarter-column, 2 chains ----
    float c0[8], c1[8];
#pragma unroll
    for (int q = 0; q < 8; q++) { c0[q] = 3.4e38f; c1[q] = 3.4e38f; }
    float mx = 0.f;
    const float* base = D + (size_t)(h * 64) * N_TOK + col;
    for (int jj = 0; jj < 64; jj += 2) {
        float d0 = base[(size_t)(jj + 0) * N_TOK];
        float d1 = base[(size_t)(jj + 1) * N_TOK];
        mx = fmaxf(mx, fmaxf(d0, d1));
        INS8(c0, d0); INS8(c1, d1);
    }
#pragma unroll
    for (int q = 0; q < 8; q++) { INS8(c0, c1[q]); }
#pragma unroll
    for (int q = 0; q < 8; q++) lists[q][tid] = c0[q];
    // dmax: wave shuffle-reduce, then 16-entry LDS
#pragma unroll
    for (int off = 32; off > 0; off >>= 1) mx = fmaxf(mx, __shfl_xor(mx, off));
    if (lane == 0) rmax16[wid] = mx;
    __syncthreads();
    float dmax = rmax16[0];
#pragma unroll
    for (int w = 1; w < 16; w++) dmax = fmaxf(dmax, rmax16[w]);

    if (h == 0) {
#pragma unroll
        for (int s = 1; s < 4; s++)
#pragma unroll
            for (int q = 0; q < 8; q++) { float v = lists[q][col + s * 256]; INS8(c0, v); }
        float s2 = 0.f;
#pragma unroll
        for (int q = 0; q < 8; q++) s2 += c0[q] * c0[q];
        dens_s[col] = expf(-s2 / (float)KNN1);
    }
    __syncthreads();
    const float dens = dens_s[col];

    // ---- pass 2: parent distance over this quarter, 2 chains ----
    float p0 = dmax, p1 = dmax;
    const float* dsh = dens_s + h * 64;
    for (int jj = 0; jj < 64; jj += 2) {
        float d0 = base[(size_t)(jj + 0) * N_TOK];
        float d1 = base[(size_t)(jj + 1) * N_TOK];
        p0 = (dsh[jj + 0] > dens) ? fminf(p0, d0) : p0;
        p1 = (dsh[jj + 1] > dens) ? fminf(p1, d1) : p1;
    }
    red[tid] = fminf(p0, p1);
    __syncthreads();
    float score = 0.f;
    if (h == 0)
        score = fminf(fminf(red[col], red[col + 256]),
                      fminf(red[col + 512], red[col + 768])) * dens;

    // ---- top-16 (desc, ties -> lowest index) ----
    unsigned long long key = 0;
    if (h == 0)
        key = ((unsigned long long)__float_as_uint(score) << 32) | (unsigned)(65535 - col);
    for (int k = 0; k < CN1; k++) {
        unsigned long long mm = key;
#pragma unroll
        for (int off = 32; off > 0; off >>= 1) {
            unsigned long long o = __shfl_xor(mm, off);
            mm = (o > mm) ? o : mm;
        }
        if (lane == 0) wred[wid] = mm;
        __syncthreads();
        unsigned long long b = wred[0];
#pragma unroll
        for (int w = 1; w < 16; w++) b = (wred[w] > b) ? wred[w] : b;
        int idx = 65535 - (int)(b & 0xFFFFull);
        if (tid == 0) centers[k] = idx;
        if (tid == idx) key = 0;
        __syncthreads();
    }

    // ---- assign + member lists (h==0 threads; barriers unconditional) ----
    int bk = 0;
    if (h == 0) {
        float bd = 3.4e38f;
#pragma unroll
        for (int k = 0; k < CN1; k++) {
            float d = D[(size_t)centers[k] * N_TOK + col];
            if (d < bd) { bd = d; bk = k; }
        }
#pragma unroll
        for (int k = 0; k < CN1; k++) if (col == centers[k]) bk = k;
        bks[col] = bk;
    }
    __syncthreads();
    if (tid < CN1) {
        int c = 0;
        for (int j = 0; j < N_TOK; j++) c += (bks[j] == tid);
        cnt_s[tid] = c;
    }
    __syncthreads();
    if (tid == 0) {
        int o = 0;
        for (int q = 0; q < CN1; q++) { off_s[q] = o; o += cnt_s[q]; }
    }
    __syncthreads();
    if (h == 0) {
        int rank = 0;
        for (int j = 0; j < col; j++) rank += (bks[j] == bk);
        memb[t * N_TOK + off_s[bk] + rank] = col;
    }
    if (tid < CN1) {
        cntg[t * CN1 + tid] = cnt_s[tid];
        offg[t * CN1 + tid] = off_s[tid];
    }
}

// ---------------------------------------------------------------------------
// Kernel C: merge1 via member lists, member loop unrolled x4 (4 independent
// row streams in flight; summation order preserved).
// ---------------------------------------------------------------------------
__global__ __launch_bounds__(256) void merge1_kernel(const float* __restrict__ x,
                                                     const int* __restrict__ memb,
                                                     const int* __restrict__ cntg,
                                                     const int* __restrict__ offg,
                                                     float* __restrict__ meta1) {
    const int q   = blockIdx.x;
    const int t   = blockIdx.y;
    const int tid = threadIdx.x;
    const int n    = cntg[t * CN1 + q];
    const int base = t * N_TOK + offg[t * CN1 + q];
    const int c0 = tid, c1 = tid + 256;
    const bool act1 = (c1 < C_DIM / 4);
    const float4* xb = (const float4*)(x + (size_t)t * N_TOK * C_DIM);
    const int stride4 = C_DIM / 4;

    float4 s0 = {0.f, 0.f, 0.f, 0.f};
    float4 s1 = {0.f, 0.f, 0.f, 0.f};
    int m = 0;
    for (; m + 4 <= n; m += 4) {
        int r0 = memb[base + m + 0];
        int r1 = memb[base + m + 1];
        int r2 = memb[base + m + 2];
        int r3 = memb[base + m + 3];
        float4 a0 = xb[(size_t)r0 * stride4 + c0];
        float4 a1 = xb[(size_t)r1 * stride4 + c0];
        float4 a2 = xb[(size_t)r2 * stride4 + c0];
        float4 a3 = xb[(size_t)r3 * stride4 + c0];
        s0.x += a0.x; s0.y += a0.y; s0.z += a0.z; s0.w += a0.w;
        s0.x += a1.x; s0.y += a1.y; s0.z += a1.z; s0.w += a1.w;
        s0.x += a2.x; s0.y += a2.y; s0.z += a2.z; s0.w += a2.w;
        s0.x += a3.x; s0.y += a3.y; s0.z += a3.z; s0.w += a3.w;
        if (act1) {
            float4 b0 = xb[(size_t)r0 * stride4 + c1];
            float4 b1 = xb[(size_t)r1 * stride4 + c1];
            float4 b2 = xb[(size_t)r2 * stride4 + c1];
            float4 b3 = xb[(size_t)r3 * stride4 + c1];
            s1.x += b0.x; s1.y += b0.y; s1.z += b0.z; s1.w += b0.w;
            s1.x += b1.x; s1.y += b1.y; s1.z += b1.z; s1.w += b1.w;
            s1.x += b2.x; s1.y += b2.y; s1.z += b2.z; s1.w += b2.w;
            s1.x += b3.x; s1.y += b3.y; s1.z += b3.z; s1.w += b3.w;
        }
    }
    for (; m < n; m++) {
        int r0 = memb[base + m];
        float4 a0 = xb[(size_t)r0 * stride4 + c0];
        s0.x += a0.x; s0.y += a0.y; s0.z += a0.z; s0.w += a0.w;
        if (act1) {
            float4 b0 = xb[(size_t)r0 * stride4 + c1];
            s1.x += b0.x; s1.y += b0.y; s1.z += b0.z; s1.w += b0.w;
        }
    }
    float w = 1.0f / ((float)n + 1e-6f);
    float4* mr = (float4*)(meta1 + ((size_t)t * CN1 + q) * C_DIM);
    float4 o0; o0.x = s0.x * w; o0.y = s0.y * w; o0.z = s0.z * w; o0.w = s0.w * w;
    mr[c0] = o0;
    if (act1) {
        float4 o1; o1.x = s1.x * w; o1.y = s1.y * w; o1.z = s1.z * w; o1.w = s1.w * w;
        mr[c1] = o1;
    }
}

// ---------------------------------------------------------------------------
// Kernel DE: layer-2 DPC + merge2 + modulation + grouped output.
// NOW grid 256 = 2 blocks per batch: both twin blocks redundantly compute the
// cheap phases (pairwise dots, DPC-2, scatter-mean, modulation — deterministic,
// identical results), and split the heavy grouped-output phase by channel half.
// Doubles CU coverage of the output phase (was 128 blocks = half chip idle).
// ---------------------------------------------------------------------------
__global__ __launch_bounds__(1024) void layer2_kernel(const float* __restrict__ meta1,
                                                      const float* __restrict__ score_w,
                                                      const float* __restrict__ score_b,
                                                      float* __restrict__ out) {
    const int t   = blockIdx.x & 127;   // batch
    const int bh  = blockIdx.x >> 7;    // channel half 0/1
    const int tid = threadIdx.x;        // 0..1023
    const float* M = meta1 + (size_t)t * CN1 * C_DIM;

    __shared__ float buf[CN1][132];
    __shared__ float d2s[CN1][CN1];
    __shared__ float m2[CN2][C_DIM];
    __shared__ float dens[CN1], scor[CN1], nrm[CN1], rmx[CN1];
    __shared__ int   centers[CN2], idx2s[CN1], cnt2[CN2];
    __shared__ float modu[CN2], msum[CN2];
    __shared__ int   srcRow[NOUT], cidArr[NOUT];
    __shared__ float dmax_sh;

    const int ti = (tid < 256) ? (tid >> 4) : 0;
    const int tj = tid & 15;

    // ---- pairwise dots (threads 0-255 own one (i,j) pair; all stage) ----
    float acc = 0.f;
    for (int c0 = 0; c0 < C_DIM; c0 += 128) {
        for (int e = tid; e < CN1 * 128; e += 1024) {
            int r = e >> 7, c = e & 127;
            buf[r][c] = M[(size_t)r * C_DIM + c0 + c];
        }
        __syncthreads();
        if (tid < 256) {
#pragma unroll
            for (int cc = 0; cc < 128; cc += 4) {
                float4 a = *(const float4*)&buf[ti][cc];
                float4 b = *(const float4*)&buf[tj][cc];
                acc += a.x * b.x + a.y * b.y + a.z * b.z + a.w * b.w;
            }
        }
        __syncthreads();
    }
    if (tid < 256 && ti == tj) nrm[ti] = acc;
    __syncthreads();

    const float inv_sqrtC = 1.0f / sqrtf((float)C_DIM);
    if (tid < 256) {
        float d2 = nrm[ti] + nrm[tj] - 2.f * acc;
        d2s[ti][tj] = sqrtf(fmaxf(d2, 0.f)) * inv_sqrtC;
    }
    __syncthreads();

    if (tid < CN1) {
        float m0 = 3.4e38f, m1 = 3.4e38f, m2v = 3.4e38f, mx = 0.f;
        for (int j = 0; j < CN1; j++) {
            float d = d2s[tid][j];
            mx = fmaxf(mx, d);
            if (d < m2v) {
                m2v = d;
                if (m2v < m1) { float tmp = m2v; m2v = m1; m1 = tmp; }
                if (m1 < m0)  { float tmp = m1;  m1 = m0;  m0 = tmp; }
            }
        }
        dens[tid] = expf(-(m0 * m0 + m1 * m1 + m2v * m2v) / (float)KNN2);
        rmx[tid] = mx;
    }
    __syncthreads();
    if (tid == 0) {
        float g = 0.f;
        for (int j = 0; j < CN1; j++) g = fmaxf(g, rmx[j]);
        dmax_sh = g;
    }
    __syncthreads();

    if (tid < CN1) {
        float di = dens[tid];
        float pd = dmax_sh;
        for (int j = 0; j < CN1; j++)
            if (dens[j] > di) pd = fminf(pd, d2s[tid][j]);
        scor[tid] = pd * di;
    }
    __syncthreads();

    if (tid == 0) {
        for (int k = 0; k < CN2; k++) {
            float best = -3.4e38f; int bi = 0;
            for (int j = 0; j < CN1; j++)
                if (scor[j] > best) { best = scor[j]; bi = j; }
            centers[k] = bi;
            scor[bi] = -3.4e38f;
        }
    }
    __syncthreads();

    if (tid < CN1) {
        float bd = 3.4e38f; int bk = 0;
#pragma unroll
        for (int k = 0; k < CN2; k++) {
            float d = d2s[centers[k]][tid];
            if (d < bd) { bd = d; bk = k; }
        }
#pragma unroll
        for (int k = 0; k < CN2; k++) if (tid == centers[k]) bk = k;
        idx2s[tid] = bk;
    }
    __syncthreads();

    if (tid == 0) {
        for (int v = 0; v < CN2; v++) cnt2[v] = 0;
        for (int i = 0; i < CN1; i++) cnt2[idx2s[i]]++;
        int slot = 0;
        for (int v = 0; v < CN2; v++) {
            srcRow[slot] = CN1 + v; cidArr[slot] = v; slot++;
            for (int i = 0; i < CN1; i++)
                if (idx2s[i] == v) { srcRow[slot] = i; cidArr[slot] = v; slot++; }
        }
        for (int v = 0; v < CN2; v++) msum[v] = 0.f;
    }
    __syncthreads();

    // ---- meta2 scatter-mean + channel sums (full C_DIM in both twins:
    //      msum must cover all channels for the modulation softmax) ----
    float ls[CN2] = {0.f, 0.f, 0.f, 0.f, 0.f, 0.f};
    for (int ch = tid; ch < C_DIM; ch += 1024) {
        float a6[CN2] = {0.f, 0.f, 0.f, 0.f, 0.f, 0.f};
        for (int r = 0; r < CN1; r++) {
            float v = M[(size_t)r * C_DIM + ch];
            int c = idx2s[r];
#pragma unroll
            for (int q = 0; q < CN2; q++) a6[q] += (c == q) ? v : 0.f;
        }
#pragma unroll
        for (int q = 0; q < CN2; q++) {
            float mv = a6[q] / ((float)cnt2[q] + 1e-6f);
            m2[q][ch] = mv;
            ls[q] += mv;
        }
    }
#pragma unroll
    for (int q = 0; q < CN2; q++) atomicAdd(&msum[q], ls[q]);
    __syncthreads();

    if (tid == 0) {
        float mean[CN2], lg[CN2];
        for (int v = 0; v < CN2; v++) mean[v] = msum[v] / (float)C_DIM;
        float mxl = -3.4e38f;
        for (int u = 0; u < CN2; u++) {
            float s = score_b[u];
            for (int v = 0; v < CN2; v++) s += mean[v] * score_w[u * CN2 + v];
            lg[u] = s;
            mxl = fmaxf(mxl, s);
        }
        float den = 0.f;
        for (int u = 0; u < CN2; u++) { lg[u] = expf(lg[u] - mxl); den += lg[u]; }
        for (int u = 0; u < CN2; u++) modu[u] = lg[u] / den;
    }
    __syncthreads();

    // ---- grouped, scaled output: this block writes channel half bh ----
    const int chLo = bh * (C_DIM / 2);
    const int chHi = chLo + (C_DIM / 2);
    float* ob = out + (size_t)t * NOUT * C_DIM;
    for (int ch = chLo + tid; ch < chHi; ch += 1024) {
#pragma unroll
        for (int s = 0; s < NOUT; s++) {
            int r = srcRow[s];
            float v = (r < CN1) ? M[(size_t)r * C_DIM + ch] : m2[r - CN1][ch];
            ob[(size_t)s * C_DIM + ch] = v * modu[cidArr[s]];
        }
    }
}

// ---------------------------------------------------------------------------
extern "C" void kernel_launch(void* const* d_in, const int* in_sizes, int n_in,
                              void* d_out, int out_size, void* d_ws, size_t ws_size,
                              hipStream_t stream) {
    const float* x  = (const float*)d_in[0];   // [128,256,1408]
    const float* sw = (const float*)d_in[1];   // [6,6]
    const float* sb = (const float*)d_in[2];   // [6]
    float* out = (float*)d_out;                // [128,22,1408]

    float* ws     = (float*)d_ws;
    float* dist   = ws;                                          // 8,388,608 f
    float* meta1  = dist + (size_t)T_BATCH * N_TOK * N_TOK;      // 2,883,584 f
    int*   memb   = (int*)(meta1 + (size_t)T_BATCH * CN1 * C_DIM); // 32768 i
    int*   cntg   = memb + (size_t)T_BATCH * N_TOK;              // 2048 i
    int*   offg   = cntg + T_BATCH * CN1;                        // 2048 i

    gemm_dist_sym<<<1280, 256, 0, stream>>>(x, dist);
    dpc1_fused<<<T_BATCH, 1024, 0, stream>>>(dist, memb, cntg, offg);
    merge1_kernel<<<dim3(CN1, T_BATCH), 256, 0, stream>>>(x, memb, cntg, offg, meta1);
    layer2_kernel<<<2 * T_BATCH, 1024, 0, stream>>>(meta1, sw, sb, out);
}

// Round 9
// 412.984 us; speedup vs baseline: 1.0899x; 1.0153x over previous
//
#include <hip/hip_runtime.h>
#include <math.h>

#define T_BATCH 128
#define N_TOK   256
#define C_DIM   1408
#define CN1     16
#define KNN1    8
#define CN2     6
#define KNN2    3
#define NOUT    22   // CN2 + CN1
#define LS      44   // LDS row stride in shorts (22 words), 8B-aligned rows

typedef __attribute__((ext_vector_type(4))) short sh4;
typedef __attribute__((ext_vector_type(8))) short sh8;
typedef __attribute__((ext_vector_type(4))) float f32x4;
typedef __fp16 h2v __attribute__((ext_vector_type(2)));
typedef __fp16 h8v __attribute__((ext_vector_type(8)));

union frag_u { sh4 h[2]; sh8 v; };
union h8u { sh8 s; h8v h; };
union h2u { h2v h; unsigned u; };

__device__ inline h8v ld_frag(const short* p) {
    frag_u u;
    u.h[0] = *(const sh4*)p;
    u.h[1] = *(const sh4*)(p + 4);
    h8u o; o.s = u.v;
    return o.h;
}

// f16 two-term split of a PAIR of fp32 -> packed f16 hi pair + f16 lo pair.
// ~6 VALU vs ~11 for the bf16 shift/round split; accuracy strictly better
// (hi+lo covers ~22 mantissa bits vs bf16's ~16). Same packed layout as before.
__device__ inline void split2(float v0, float v1, unsigned& hip, unsigned& lop) {
    h2v h = __builtin_amdgcn_cvt_pkrtz(v0, v1);
    float r0 = v0 - (float)h[0];
    float r1 = v1 - (float)h[1];
    h2v l = __builtin_amdgcn_cvt_pkrtz(r0, r1);
    h2u uh, ul;
    uh.h = h; ul.h = l;
    hip = uh.u;
    lop = ul.u;
}

// branchless insert of v into ascending 8-list m (keeps 8 smallest)
#define INS8(m, v) {                                   \
    float _x = (v);                                    \
    _Pragma("unroll")                                  \
    for (int _q = 0; _q < 8; _q++) {                   \
        float _lo = fminf(m[_q], _x);                  \
        _x = fmaxf(m[_q], _x);                         \
        m[_q] = _lo;                                   \
    }                                                  \
}

// ---------------------------------------------------------------------------
// Kernel A: dist via f16x3 MFMA, 64x64 tiles, upper-tri pairs only.
// EXACT r0/r8 structure (best measured): grid 1280 XCD-swizzled, 256 thr,
// LS=44, scattered staging, T14 prefetch, 2 barriers/K-step.
// ONLY change vs r8: split2 uses cvt_pkrtz f16 split (cheaper VALU) and the
// MFMA intrinsic is 16x16x32_f16. LDS layout/addressing byte-identical.
// Do NOT reapply: 128x256 panel, coalesced staging, dbuf, LS=40 (all slower).
// ---------------------------------------------------------------------------
__global__ __launch_bounds__(256, 4) void gemm_dist_sym(const float* __restrict__ x,
                                                        float* __restrict__ dist) {
    const int id = blockIdx.x;
    const int r  = id & 7;
    const int q8 = id >> 3;          // 0..159
    const int p  = q8 % 10;
    const int tt = q8 / 10;          // 0..15
    const int t  = tt * 8 + r;
    const int bi = (p < 4) ? 0 : (p < 7) ? 1 : (p < 9) ? 2 : 3;
    const int bj = (p < 4) ? p : (p < 7) ? p - 3 : (p < 9) ? p - 5 : 3;
    const int i0 = bi * 64, j0 = bj * 64;
    const bool diag = (bi == bj);
    const float* X = x + (size_t)t * N_TOK * C_DIM;

    __shared__ short Ahi[64 * LS], Alo[64 * LS], Bhi[64 * LS], Blo[64 * LS];
    __shared__ float nred[512];
    __shared__ float snA[64], snB[64];

    const int tid  = threadIdx.x;
    const int wave = tid >> 6;
    const int lane = tid & 63;
    const int qr   = wave >> 1;
    const int qc   = wave & 1;
    const int srow = tid >> 2;
    const int sq   = tid & 3;
    const int fr   = lane & 15;
    const int fq   = lane >> 4;

    const short* BhiS = diag ? Ahi : Bhi;
    const short* BloS = diag ? Alo : Blo;

    f32x4 acc[2][2];
#pragma unroll
    for (int a = 0; a < 2; a++)
#pragma unroll
        for (int b = 0; b < 2; b++) acc[a][b] = (f32x4){0.f, 0.f, 0.f, 0.f};

    const float* Arow = X + (size_t)(i0 + srow) * C_DIM + sq * 8;
    const float* Brow = X + (size_t)(j0 + srow) * C_DIM + sq * 8;
    float nA = 0.f, nB = 0.f;

    // --- prologue: preload K-step 0 into registers ---
    float4 a0 = *(const float4*)(Arow + 0);
    float4 a1 = *(const float4*)(Arow + 4);
    float4 b0 = {0.f, 0.f, 0.f, 0.f}, b1 = {0.f, 0.f, 0.f, 0.f};
    if (!diag) {
        b0 = *(const float4*)(Brow + 0);
        b1 = *(const float4*)(Brow + 4);
    }

    for (int k0 = 0; k0 < C_DIM; k0 += 32) {
        float av[8], bv[8];
        av[0] = a0.x; av[1] = a0.y; av[2] = a0.z; av[3] = a0.w;
        av[4] = a1.x; av[5] = a1.y; av[6] = a1.z; av[7] = a1.w;
#pragma unroll
        for (int e = 0; e < 8; e++) nA += av[e] * av[e];
        unsigned ah[4], al[4], bh[4], bl[4];
#pragma unroll
        for (int q = 0; q < 4; q++) split2(av[2 * q], av[2 * q + 1], ah[q], al[q]);
        if (!diag) {
            bv[0] = b0.x; bv[1] = b0.y; bv[2] = b0.z; bv[3] = b0.w;
            bv[4] = b1.x; bv[5] = b1.y; bv[6] = b1.z; bv[7] = b1.w;
#pragma unroll
            for (int e = 0; e < 8; e++) nB += bv[e] * bv[e];
#pragma unroll
            for (int q = 0; q < 4; q++) split2(bv[2 * q], bv[2 * q + 1], bh[q], bl[q]);
        }
        __syncthreads();
        {
            unsigned* AH = (unsigned*)&Ahi[srow * LS + sq * 8];
            unsigned* AL = (unsigned*)&Alo[srow * LS + sq * 8];
#pragma unroll
            for (int q = 0; q < 4; q++) { AH[q] = ah[q]; AL[q] = al[q]; }
            if (!diag) {
                unsigned* BH = (unsigned*)&Bhi[srow * LS + sq * 8];
                unsigned* BL = (unsigned*)&Blo[srow * LS + sq * 8];
#pragma unroll
                for (int q = 0; q < 4; q++) { BH[q] = bh[q]; BL[q] = bl[q]; }
            }
        }
        __syncthreads();

        // --- T14: issue next K-step's global loads before ds_read/MFMA ---
        const int k1 = k0 + 32;
        if (k1 < C_DIM) {
            a0 = *(const float4*)(Arow + k1);
            a1 = *(const float4*)(Arow + k1 + 4);
            if (!diag) {
                b0 = *(const float4*)(Brow + k1);
                b1 = *(const float4*)(Brow + k1 + 4);
            }
        }

        h8v fAh[2], fAl[2], fBh[2], fBl[2];
#pragma unroll
        for (int mt = 0; mt < 2; mt++) {
            int ro = (qr * 32 + mt * 16 + fr) * LS + fq * 8;
            fAh[mt] = ld_frag(&Ahi[ro]);
            fAl[mt] = ld_frag(&Alo[ro]);
            int co = (qc * 32 + mt * 16 + fr) * LS + fq * 8;
            fBh[mt] = ld_frag(&BhiS[co]);
            fBl[mt] = ld_frag(&BloS[co]);
        }
#pragma unroll
        for (int mt = 0; mt < 2; mt++)
#pragma unroll
            for (int nt = 0; nt < 2; nt++) {
                acc[mt][nt] = __builtin_amdgcn_mfma_f32_16x16x32_f16(fAh[mt], fBh[nt], acc[mt][nt], 0, 0, 0);
                acc[mt][nt] = __builtin_amdgcn_mfma_f32_16x16x32_f16(fAh[mt], fBl[nt], acc[mt][nt], 0, 0, 0);
                acc[mt][nt] = __builtin_amdgcn_mfma_f32_16x16x32_f16(fAl[mt], fBh[nt], acc[mt][nt], 0, 0, 0);
            }
    }

    nred[tid] = nA;
    nred[256 + tid] = diag ? nA : nB;
    __syncthreads();
    if (tid < 64) {
        snA[tid] = nred[4 * tid] + nred[4 * tid + 1] + nred[4 * tid + 2] + nred[4 * tid + 3];
        snB[tid] = nred[256 + 4 * tid] + nred[256 + 4 * tid + 1]
                 + nred[256 + 4 * tid + 2] + nred[256 + 4 * tid + 3];
    }
    __syncthreads();

    const float inv_sqrtC = 1.0f / sqrtf((float)C_DIM);
    float* Dt = dist + (size_t)t * N_TOK * N_TOK;
#pragma unroll
    for (int mt = 0; mt < 2; mt++)
#pragma unroll
        for (int nt = 0; nt < 2; nt++) {
            int jl = qc * 32 + nt * 16 + fr;
            int jg = j0 + jl;
            float sqj = snB[jl];
            int il0 = qr * 32 + mt * 16 + fq * 4;
            float vv[4];
#pragma unroll
            for (int rr = 0; rr < 4; rr++) {
                int ig = i0 + il0 + rr;
                float d2 = snA[il0 + rr] + sqj - 2.0f * acc[mt][nt][rr];
                float v = (ig == jg) ? 0.0f : sqrtf(fmaxf(d2, 0.0f)) * inv_sqrtC;
                Dt[(size_t)ig * N_TOK + jg] = v;
                vv[rr] = v;
            }
            if (!diag) {
                float4 o; o.x = vv[0]; o.y = vv[1]; o.z = vv[2]; o.w = vv[3];
                *(float4*)&Dt[(size_t)jg * N_TOK + i0 + il0] = o;
            }
        }
}

// ---------------------------------------------------------------------------
// Kernel B: fused layer-1 DPC. 1024 threads/block, one block per batch.
// 4 threads per column (64-row quarter scans), 2 chains each, LDS merge.
// ---------------------------------------------------------------------------
__global__ __launch_bounds__(1024) void dpc1_fused(const float* __restrict__ dist,
                                                   int* __restrict__ memb,
                                                   int* __restrict__ cntg,
                                                   int* __restrict__ offg) {
    const int t    = blockIdx.x;
    const int tid  = threadIdx.x;    // 0..1023
    const int col  = tid & 255;
    const int h    = tid >> 8;       // row quarter 0..3
    const int lane = tid & 63;
    const int wid  = tid >> 6;       // 0..15
    const float* D = dist + (size_t)t * N_TOK * N_TOK;

    __shared__ float dens_s[N_TOK];
    __shared__ float lists[KNN1][1024];
    __shared__ float red[1024];
    __shared__ float rmax16[16];
    __shared__ unsigned long long wred[16];
    __shared__ int centers[CN1];
    __shared__ int bks[N_TOK];
    __shared__ int cnt_s[CN1], off_s[CN1];

    // ---- pass 1: 8 smallest of this quarter-column, 2 chains ----
    float c0[8], c1[8];
#pragma unroll
    for (int q = 0; q < 8; q++) { c0[q] = 3.4e38f; c1[q] = 3.4e38f; }
    float mx = 0.f;
    const float* base = D + (size_t)(h * 64) * N_TOK + col;
    for (int jj = 0; jj < 64; jj += 2) {
        float d0 = base[(size_t)(jj + 0) * N_TOK];
        float d1 = base[(size_t)(jj + 1) * N_TOK];
        mx = fmaxf(mx, fmaxf(d0, d1));
        INS8(c0, d0); INS8(c1, d1);
    }
#pragma unroll
    for (int q = 0; q < 8; q++) { INS8(c0, c1[q]); }
#pragma unroll
    for (int q = 0; q < 8; q++) lists[q][tid] = c0[q];
    // dmax: wave shuffle-reduce, then 16-entry LDS
#pragma unroll
    for (int off = 32; off > 0; off >>= 1) mx = fmaxf(mx, __shfl_xor(mx, off));
    if (lane == 0) rmax16[wid] = mx;
    __syncthreads();
    float dmax = rmax16[0];
#pragma unroll
    for (int w = 1; w < 16; w++) dmax = fmaxf(dmax, rmax16[w]);

    if (h == 0) {
#pragma unroll
        for (int s = 1; s < 4; s++)
#pragma unroll
            for (int q = 0; q < 8; q++) { float v = lists[q][col + s * 256]; INS8(c0, v); }
        float s2 = 0.f;
#pragma unroll
        for (int q = 0; q < 8; q++) s2 += c0[q] * c0[q];
        dens_s[col] = expf(-s2 / (float)KNN1);
    }
    __syncthreads();
    const float dens = dens_s[col];

    // ---- pass 2: parent distance over this quarter, 2 chains ----
    float p0 = dmax, p1 = dmax;
    const float* dsh = dens_s + h * 64;
    for (int jj = 0; jj < 64; jj += 2) {
        float d0 = base[(size_t)(jj + 0) * N_TOK];
        float d1 = base[(size_t)(jj + 1) * N_TOK];
        p0 = (dsh[jj + 0] > dens) ? fminf(p0, d0) : p0;
        p1 = (dsh[jj + 1] > dens) ? fminf(p1, d1) : p1;
    }
    red[tid] = fminf(p0, p1);
    __syncthreads();
    float score = 0.f;
    if (h == 0)
        score = fminf(fminf(red[col], red[col + 256]),
                      fminf(red[col + 512], red[col + 768])) * dens;

    // ---- top-16 (desc, ties -> lowest index) ----
    unsigned long long key = 0;
    if (h == 0)
        key = ((unsigned long long)__float_as_uint(score) << 32) | (unsigned)(65535 - col);
    for (int k = 0; k < CN1; k++) {
        unsigned long long mm = key;
#pragma unroll
        for (int off = 32; off > 0; off >>= 1) {
            unsigned long long o = __shfl_xor(mm, off);
            mm = (o > mm) ? o : mm;
        }
        if (lane == 0) wred[wid] = mm;
        __syncthreads();
        unsigned long long b = wred[0];
#pragma unroll
        for (int w = 1; w < 16; w++) b = (wred[w] > b) ? wred[w] : b;
        int idx = 65535 - (int)(b & 0xFFFFull);
        if (tid == 0) centers[k] = idx;
        if (tid == idx) key = 0;
        __syncthreads();
    }

    // ---- assign + member lists (h==0 threads; barriers unconditional) ----
    int bk = 0;
    if (h == 0) {
        float bd = 3.4e38f;
#pragma unroll
        for (int k = 0; k < CN1; k++) {
            float d = D[(size_t)centers[k] * N_TOK + col];
            if (d < bd) { bd = d; bk = k; }
        }
#pragma unroll
        for (int k = 0; k < CN1; k++) if (col == centers[k]) bk = k;
        bks[col] = bk;
    }
    __syncthreads();
    if (tid < CN1) {
        int c = 0;
        for (int j = 0; j < N_TOK; j++) c += (bks[j] == tid);
        cnt_s[tid] = c;
    }
    __syncthreads();
    if (tid == 0) {
        int o = 0;
        for (int q = 0; q < CN1; q++) { off_s[q] = o; o += cnt_s[q]; }
    }
    __syncthreads();
    if (h == 0) {
        int rank = 0;
        for (int j = 0; j < col; j++) rank += (bks[j] == bk);
        memb[t * N_TOK + off_s[bk] + rank] = col;
    }
    if (tid < CN1) {
        cntg[t * CN1 + tid] = cnt_s[tid];
        offg[t * CN1 + tid] = off_s[tid];
    }
}

// ---------------------------------------------------------------------------
// Kernel C: merge1 via member lists, member loop unrolled x4 (4 independent
// row streams in flight; summation order preserved).
// ---------------------------------------------------------------------------
__global__ __launch_bounds__(256) void merge1_kernel(const float* __restrict__ x,
                                                     const int* __restrict__ memb,
                                                     const int* __restrict__ cntg,
                                                     const int* __restrict__ offg,
                                                     float* __restrict__ meta1) {
    const int q   = blockIdx.x;
    const int t   = blockIdx.y;
    const int tid = threadIdx.x;
    const int n    = cntg[t * CN1 + q];
    const int base = t * N_TOK + offg[t * CN1 + q];
    const int c0 = tid, c1 = tid + 256;
    const bool act1 = (c1 < C_DIM / 4);
    const float4* xb = (const float4*)(x + (size_t)t * N_TOK * C_DIM);
    const int stride4 = C_DIM / 4;

    float4 s0 = {0.f, 0.f, 0.f, 0.f};
    float4 s1 = {0.f, 0.f, 0.f, 0.f};
    int m = 0;
    for (; m + 4 <= n; m += 4) {
        int r0 = memb[base + m + 0];
        int r1 = memb[base + m + 1];
        int r2 = memb[base + m + 2];
        int r3 = memb[base + m + 3];
        float4 a0 = xb[(size_t)r0 * stride4 + c0];
        float4 a1 = xb[(size_t)r1 * stride4 + c0];
        float4 a2 = xb[(size_t)r2 * stride4 + c0];
        float4 a3 = xb[(size_t)r3 * stride4 + c0];
        s0.x += a0.x; s0.y += a0.y; s0.z += a0.z; s0.w += a0.w;
        s0.x += a1.x; s0.y += a1.y; s0.z += a1.z; s0.w += a1.w;
        s0.x += a2.x; s0.y += a2.y; s0.z += a2.z; s0.w += a2.w;
        s0.x += a3.x; s0.y += a3.y; s0.z += a3.z; s0.w += a3.w;
        if (act1) {
            float4 b0 = xb[(size_t)r0 * stride4 + c1];
            float4 b1 = xb[(size_t)r1 * stride4 + c1];
            float4 b2 = xb[(size_t)r2 * stride4 + c1];
            float4 b3 = xb[(size_t)r3 * stride4 + c1];
            s1.x += b0.x; s1.y += b0.y; s1.z += b0.z; s1.w += b0.w;
            s1.x += b1.x; s1.y += b1.y; s1.z += b1.z; s1.w += b1.w;
            s1.x += b2.x; s1.y += b2.y; s1.z += b2.z; s1.w += b2.w;
            s1.x += b3.x; s1.y += b3.y; s1.z += b3.z; s1.w += b3.w;
        }
    }
    for (; m < n; m++) {
        int r0 = memb[base + m];
        float4 a0 = xb[(size_t)r0 * stride4 + c0];
        s0.x += a0.x; s0.y += a0.y; s0.z += a0.z; s0.w += a0.w;
        if (act1) {
            float4 b0 = xb[(size_t)r0 * stride4 + c1];
            s1.x += b0.x; s1.y += b0.y; s1.z += b0.z; s1.w += b0.w;
        }
    }
    float w = 1.0f / ((float)n + 1e-6f);
    float4* mr = (float4*)(meta1 + ((size_t)t * CN1 + q) * C_DIM);
    float4 o0; o0.x = s0.x * w; o0.y = s0.y * w; o0.z = s0.z * w; o0.w = s0.w * w;
    mr[c0] = o0;
    if (act1) {
        float4 o1; o1.x = s1.x * w; o1.y = s1.y * w; o1.z = s1.z * w; o1.w = s1.w * w;
        mr[c1] = o1;
    }
}

// ---------------------------------------------------------------------------
// Kernel DE: layer-2 DPC + merge2 + modulation + grouped output.
// Grid 256 = 2 blocks per batch: twins redundantly compute the cheap phases
// (deterministic, identical results) and split the output phase by channel half.
// ---------------------------------------------------------------------------
__global__ __launch_bounds__(1024) void layer2_kernel(const float* __restrict__ meta1,
                                                      const float* __restrict__ score_w,
                                                      const float* __restrict__ score_b,
                                                      float* __restrict__ out) {
    const int t   = blockIdx.x & 127;   // batch
    const int bh  = blockIdx.x >> 7;    // channel half 0/1
    const int tid = threadIdx.x;        // 0..1023
    const float* M = meta1 + (size_t)t * CN1 * C_DIM;

    __shared__ float buf[CN1][132];
    __shared__ float d2s[CN1][CN1];
    __shared__ float m2[CN2][C_DIM];
    __shared__ float dens[CN1], scor[CN1], nrm[CN1], rmx[CN1];
    __shared__ int   centers[CN2], idx2s[CN1], cnt2[CN2];
    __shared__ float modu[CN2], msum[CN2];
    __shared__ int   srcRow[NOUT], cidArr[NOUT];
    __shared__ float dmax_sh;

    const int ti = (tid < 256) ? (tid >> 4) : 0;
    const int tj = tid & 15;

    // ---- pairwise dots (threads 0-255 own one (i,j) pair; all stage) ----
    float acc = 0.f;
    for (int c0 = 0; c0 < C_DIM; c0 += 128) {
        for (int e = tid; e < CN1 * 128; e += 1024) {
            int r = e >> 7, c = e & 127;
            buf[r][c] = M[(size_t)r * C_DIM + c0 + c];
        }
        __syncthreads();
        if (tid < 256) {
#pragma unroll
            for (int cc = 0; cc < 128; cc += 4) {
                float4 a = *(const float4*)&buf[ti][cc];
                float4 b = *(const float4*)&buf[tj][cc];
                acc += a.x * b.x + a.y * b.y + a.z * b.z + a.w * b.w;
            }
        }
        __syncthreads();
    }
    if (tid < 256 && ti == tj) nrm[ti] = acc;
    __syncthreads();

    const float inv_sqrtC = 1.0f / sqrtf((float)C_DIM);
    if (tid < 256) {
        float d2 = nrm[ti] + nrm[tj] - 2.f * acc;
        d2s[ti][tj] = sqrtf(fmaxf(d2, 0.f)) * inv_sqrtC;
    }
    __syncthreads();

    if (tid < CN1) {
        float m0 = 3.4e38f, m1 = 3.4e38f, m2v = 3.4e38f, mx = 0.f;
        for (int j = 0; j < CN1; j++) {
            float d = d2s[tid][j];
            mx = fmaxf(mx, d);
            if (d < m2v) {
                m2v = d;
                if (m2v < m1) { float tmp = m2v; m2v = m1; m1 = tmp; }
                if (m1 < m0)  { float tmp = m1;  m1 = m0;  m0 = tmp; }
            }
        }
        dens[tid] = expf(-(m0 * m0 + m1 * m1 + m2v * m2v) / (float)KNN2);
        rmx[tid] = mx;
    }
    __syncthreads();
    if (tid == 0) {
        float g = 0.f;
        for (int j = 0; j < CN1; j++) g = fmaxf(g, rmx[j]);
        dmax_sh = g;
    }
    __syncthreads();

    if (tid < CN1) {
        float di = dens[tid];
        float pd = dmax_sh;
        for (int j = 0; j < CN1; j++)
            if (dens[j] > di) pd = fminf(pd, d2s[tid][j]);
        scor[tid] = pd * di;
    }
    __syncthreads();

    if (tid == 0) {
        for (int k = 0; k < CN2; k++) {
            float best = -3.4e38f; int bi = 0;
            for (int j = 0; j < CN1; j++)
                if (scor[j] > best) { best = scor[j]; bi = j; }
            centers[k] = bi;
            scor[bi] = -3.4e38f;
        }
    }
    __syncthreads();

    if (tid < CN1) {
        float bd = 3.4e38f; int bk = 0;
#pragma unroll
        for (int k = 0; k < CN2; k++) {
            float d = d2s[centers[k]][tid];
            if (d < bd) { bd = d; bk = k; }
        }
#pragma unroll
        for (int k = 0; k < CN2; k++) if (tid == centers[k]) bk = k;
        idx2s[tid] = bk;
    }
    __syncthreads();

    if (tid == 0) {
        for (int v = 0; v < CN2; v++) cnt2[v] = 0;
        for (int i = 0; i < CN1; i++) cnt2[idx2s[i]]++;
        int slot = 0;
        for (int v = 0; v < CN2; v++) {
            srcRow[slot] = CN1 + v; cidArr[slot] = v; slot++;
            for (int i = 0; i < CN1; i++)
                if (idx2s[i] == v) { srcRow[slot] = i; cidArr[slot] = v; slot++; }
        }
        for (int v = 0; v < CN2; v++) msum[v] = 0.f;
    }
    __syncthreads();

    // ---- meta2 scatter-mean + channel sums (full C_DIM in both twins:
    //      msum must cover all channels for the modulation softmax) ----
    float ls[CN2] = {0.f, 0.f, 0.f, 0.f, 0.f, 0.f};
    for (int ch = tid; ch < C_DIM; ch += 1024) {
        float a6[CN2] = {0.f, 0.f, 0.f, 0.f, 0.f, 0.f};
        for (int r = 0; r < CN1; r++) {
            float v = M[(size_t)r * C_DIM + ch];
            int c = idx2s[r];
#pragma unroll
            for (int q = 0; q < CN2; q++) a6[q] += (c == q) ? v : 0.f;
        }
#pragma unroll
        for (int q = 0; q < CN2; q++) {
            float mv = a6[q] / ((float)cnt2[q] + 1e-6f);
            m2[q][ch] = mv;
            ls[q] += mv;
        }
    }
#pragma unroll
    for (int q = 0; q < CN2; q++) atomicAdd(&msum[q], ls[q]);
    __syncthreads();

    if (tid == 0) {
        float mean[CN2], lg[CN2];
        for (int v = 0; v < CN2; v++) mean[v] = msum[v] / (float)C_DIM;
        float mxl = -3.4e38f;
        for (int u = 0; u < CN2; u++) {
            float s = score_b[u];
            for (int v = 0; v < CN2; v++) s += mean[v] * score_w[u * CN2 + v];
            lg[u] = s;
            mxl = fmaxf(mxl, s);
        }
        float den = 0.f;
        for (int u = 0; u < CN2; u++) { lg[u] = expf(lg[u] - mxl); den += lg[u]; }
        for (int u = 0; u < CN2; u++) modu[u] = lg[u] / den;
    }
    __syncthreads();

    // ---- grouped, scaled output: this block writes channel half bh ----
    const int chLo = bh * (C_DIM / 2);
    const int chHi = chLo + (C_DIM / 2);
    float* ob = out + (size_t)t * NOUT * C_DIM;
    for (int ch = chLo + tid; ch < chHi; ch += 1024) {
#pragma unroll
        for (int s = 0; s < NOUT; s++) {
            int r = srcRow[s];
            float v = (r < CN1) ? M[(size_t)r * C_DIM + ch] : m2[r - CN1][ch];
            ob[(size_t)s * C_DIM + ch] = v * modu[cidArr[s]];
        }
    }
}

// ---------------------------------------------------------------------------
extern "C" void kernel_launch(void* const* d_in, const int* in_sizes, int n_in,
                              void* d_out, int out_size, void* d_ws, size_t ws_size,
                              hipStream_t stream) {
    const float* x  = (const float*)d_in[0];   // [128,256,1408]
    const float* sw = (const float*)d_in[1];   // [6,6]
    const float* sb = (const float*)d_in[2];   // [6]
    float* out = (float*)d_out;                // [128,22,1408]

    float* ws     = (float*)d_ws;
    float* dist   = ws;                                          // 8,388,608 f
    float* meta1  = dist + (size_t)T_BATCH * N_TOK * N_TOK;      // 2,883,584 f
    int*   memb   = (int*)(meta1 + (size_t)T_BATCH * CN1 * C_DIM); // 32768 i
    int*   cntg   = memb + (size_t)T_BATCH * N_TOK;              // 2048 i
    int*   offg   = cntg + T_BATCH * CN1;                        // 2048 i

    gemm_dist_sym<<<1280, 256, 0, stream>>>(x, dist);
    dpc1_fused<<<T_BATCH, 1024, 0, stream>>>(dist, memb, cntg, offg);
    merge1_kernel<<<dim3(CN1, T_BATCH), 256, 0, stream>>>(x, memb, cntg, offg, meta1);
    layer2_kernel<<<2 * T_BATCH, 1024, 0, stream>>>(meta1, sw, sb, out);
}